// Round 10
// baseline (299.989 us; speedup 1.0000x reference)
//
#include <hip/hip_runtime.h>
#include <hip/hip_fp16.h>
#include <math.h>

// ---------------------------------------------------------------------------
// EquivariantNet forward — round 10.
// Exact r7 structure (known good, 292.9 us) + two safe changes:
// (1) __launch_bounds__(256,2) on k_conv: lifts the 68-VGPR ceiling so the
//     unrolled body can batch its ~110 VMEM loads (latency tolerance per
//     wave), same goal as the failed 2-tile rewrite without restructuring.
// (2) k_attn: sum-pass merged into accumulation (unnormalized exp + final
//     1/s scale) — one fewer zb pass, half the expf.
// Shapes: N=8192, E=131072, C=16, mid=16, KV=16, ckv=8, Co=8, HEADS=4, L=2
// ---------------------------------------------------------------------------

typedef _Float16 half8 __attribute__((ext_vector_type(8)));
typedef float f32x4 __attribute__((ext_vector_type(4)));

union AF {
    half8 h8;
    __half2 h2[4];
};
union U32h2 {
    unsigned u;
    __half2 h;
};

// ---------------- CSR build over edge_dst ----------------
__global__ void k_hist(const int* __restrict__ dst, int* __restrict__ counts, int E) {
    int e = blockIdx.x * 256 + threadIdx.x;
    if (e < E) atomicAdd(&counts[dst[e]], 1);
}

__global__ __launch_bounds__(1024) void k_scan(const int* __restrict__ counts,
                                               int* __restrict__ rowptr,
                                               int* __restrict__ cursor,
                                               int N, int CH) {
    __shared__ int part[1024];
    int t = threadIdx.x;
    int s = 0;
    for (int i = 0; i < CH; ++i) {
        int idx = t * CH + i;
        if (idx < N) s += counts[idx];
    }
    part[t] = s;
    __syncthreads();
    for (int off = 1; off < 1024; off <<= 1) {
        int v = (t >= off) ? part[t - off] : 0;
        __syncthreads();
        part[t] += v;
        __syncthreads();
    }
    int run = (t == 0) ? 0 : part[t - 1];
    for (int i = 0; i < CH; ++i) {
        int idx = t * CH + i;
        if (idx < N) {
            rowptr[idx] = run;
            cursor[idx] = run;
            run += counts[idx];
        }
    }
    if (t == 0) rowptr[N] = part[1023];
}

__global__ void k_scatter(const int* __restrict__ dst, int* __restrict__ cursor,
                          int* __restrict__ pose, int E) {
    int e = blockIdx.x * 256 + threadIdx.x;
    if (e < E) {
        int pos = atomicAdd(&cursor[dst[e]], 1);
        pose[e] = pos;
    }
}

// ---------------- fused init: xs copies + ef->f16 ----------------
__global__ void k_misc(const float* __restrict__ x0, const float* __restrict__ x1,
                       const float* __restrict__ ef,
                       float* __restrict__ xs0, float* __restrict__ xs1,
                       unsigned short* __restrict__ efh, int n0, int n1, int n2) {
    int i = blockIdx.x * 256 + threadIdx.x;
    if (i < n0) { xs0[i] = x0[i]; return; }
    i -= n0;
    if (i < n1) { xs1[i] = x1[i]; return; }
    i -= n1;
    if (i < n2) efh[i] = __half_as_ushort(__float2half(ef[i]));
}

// ---------------- weight permute into A-fragment order (f16) ----------------
// 52 frag-rows per conv (conv c base = c*52):
//   rows 0..3   : w1 A-frags, A[m=h][k=f]: w1[pp][f=quad*8+j][h=m], quad<2 else 0
//   rows 4..27  : fams 0..2 (fam*8+kk): h = quad*4+((j>>1)&3), i = 2kk+(j&1)
//   rows 28..51 : fam 3 (kk2 0..23):    h = quad*4+((j>>1)&3), if = 2kk2+(j&1)
__global__ void k_prepw(const float* __restrict__ kvw1, const float* __restrict__ fcw1,
                        const float* __restrict__ kvw2n, const float* __restrict__ kvw211,
                        const float* __restrict__ fcw2n, const float* __restrict__ fcw211,
                        unsigned short* __restrict__ Wfrag) {
    int t = blockIdx.x * 256 + threadIdx.x;
    if (t >= 156 * 64 * 8) return;
    int j = t & 7;
    int lane = (t >> 3) & 63;
    int row = t >> 9;
    int quad = lane >> 4, m = lane & 15;
    int c = row / 52, r = row % 52;
    int KVO = (c < 2) ? 16 : 8;
    const float* w1src = (c < 2) ? (kvw1 + c * 1024) : fcw1;
    const float* w2n = (c < 2) ? (kvw2n + c * 12288) : fcw2n;
    const float* w211 = (c < 2) ? (kvw211 + c * 12288) : fcw211;
    float v = 0.f;
    if (r < 4) {
        if (quad < 2) v = w1src[r * 256 + (quad * 8 + j) * 16 + m];
    } else if (r < 28) {
        int fam = (r - 4) >> 3, kk = (r - 4) & 7;
        int h = quad * 4 + ((j >> 1) & 3), i = 2 * kk + (j & 1);
        if (m < KVO) v = w2n[((fam * 16 + h) * KVO + m) * 16 + i];
    } else {
        int kk2 = r - 28;
        int h = quad * 4 + ((j >> 1) & 3);
        int ifx = 2 * kk2 + (j & 1);
        int i = ifx / 3, f = ifx % 3;
        if (m < KVO) v = w211[((h * KVO + m) * 16 + i) * 3 + f];
    }
    Wfrag[t] = __half_as_ushort(__float2half(v));
}

// ---------------- fused MFMA conv (+H, +z), f16, pair-shared-H builds --------
// vrow[pos][32]: [0..8) scalar d | [8..32) 8+d*3+m.  zb[pos][4]: per-head z.
template <int KVO, bool DO_Z>
__global__ __launch_bounds__(256, 2) void k_conv(
    int E,
    const int* __restrict__ src, const int* __restrict__ dst,
    const int* __restrict__ pose,
    const float* __restrict__ xs0, const float* __restrict__ xs1,
    const float* __restrict__ b00, const float* __restrict__ b01,
    const float* __restrict__ b10, const float* __restrict__ b11,
    const unsigned short* __restrict__ efh,    // (E,16) f16
    const unsigned short* __restrict__ Wfrag,  // frag-ordered weights (f16)
    int wbase,
    const float* __restrict__ q0, const float* __restrict__ q1,
    float* __restrict__ vrow, float* __restrict__ zb)
{
    // xB pairs: [wave][m][p*24 + u], u = if/2 (0..23), each uint = half2 pair
    __shared__ __align__(16) unsigned xBL[4][16 * 74];
    int tid = threadIdx.x;
    int wave = tid >> 6, lane = tid & 63;
    int tile = blockIdx.x * 4 + wave;
    if (tile * 16 >= E) return;
    int m = lane & 15, quad = lane >> 4;
    int e0 = tile * 16;
    int me = e0 + m;
    int s = src[me];
    unsigned* xw = xBL[wave];
    const half8* W8 = (const half8*)Wfrag;

    // ---- xB[p][if] = sum_q x1[i][q]*b11[p][q][f]; quad covers if [quad*12,+12) ----
    {
        float x1c[12];
        const float4* xp = (const float4*)(xs1 + (size_t)s * 48 + quad * 12);
#pragma unroll
        for (int cc = 0; cc < 3; ++cc) {
            float4 v = xp[cc];
            x1c[cc * 4 + 0] = v.x; x1c[cc * 4 + 1] = v.y;
            x1c[cc * 4 + 2] = v.z; x1c[cc * 4 + 3] = v.w;
        }
        float b11r[27];
#pragma unroll
        for (int k = 0; k < 27; ++k) b11r[k] = b11[(size_t)me * 27 + k];
#pragma unroll
        for (int p = 0; p < 3; ++p) {
            float vals[12];
#pragma unroll
            for (int i2 = 0; i2 < 4; ++i2) {
#pragma unroll
                for (int f = 0; f < 3; ++f) {
                    float a = 0.f;
#pragma unroll
                    for (int q = 0; q < 3; ++q) a += x1c[i2 * 3 + q] * b11r[p * 9 + q * 3 + f];
                    vals[i2 * 3 + f] = a;
                }
            }
            unsigned uu[6];
#pragma unroll
            for (int u = 0; u < 6; ++u) {
                U32h2 w;
                w.h = __float22half2_rn(make_float2(vals[2 * u], vals[2 * u + 1]));
                uu[u] = w.u;
            }
            int boff = m * 74 + p * 24 + quad * 6;
            *(uint2*)&xw[boff + 0] = make_uint2(uu[0], uu[1]);
            *(uint2*)&xw[boff + 2] = make_uint2(uu[2], uu[3]);
            *(uint2*)&xw[boff + 4] = make_uint2(uu[4], uu[5]);
        }
    }
    __syncthreads();

    // ---- x0 / t10 rows as natural half2 pairs (8 regs each) ----
    __half2 x0p[8], t10p[8];
    {
        const float4* p = (const float4*)(xs0 + (size_t)s * 16);
#pragma unroll
        for (int k = 0; k < 4; ++k) {
            float4 v = p[k];
            x0p[2 * k + 0] = __float22half2_rn(make_float2(v.x, v.y));
            x0p[2 * k + 1] = __float22half2_rn(make_float2(v.z, v.w));
        }
        float bq0 = b10[(size_t)me * 3 + 0], bq1 = b10[(size_t)me * 3 + 1],
              bq2 = b10[(size_t)me * 3 + 2];
        const float4* xp = (const float4*)(xs1 + (size_t)s * 48);
        float tf[16];
#pragma unroll
        for (int g = 0; g < 4; ++g) {
            float4 a = xp[g * 3 + 0], b = xp[g * 3 + 1], cc = xp[g * 3 + 2];
            float xf[12] = {a.x, a.y, a.z, a.w, b.x, b.y, b.z, b.w, cc.x, cc.y, cc.z, cc.w};
#pragma unroll
            for (int i2 = 0; i2 < 4; ++i2)
                tf[g * 4 + i2] = bq0 * xf[i2 * 3] + bq1 * xf[i2 * 3 + 1] + bq2 * xf[i2 * 3 + 2];
        }
#pragma unroll
        for (int k = 0; k < 8; ++k)
            t10p[k] = __float22half2_rn(make_float2(tf[2 * k], tf[2 * k + 1]));
    }

    // ---- H via 4 f16 MFMAs -> dup-half2 per (pp, t): H[pp][h=quad*4+t] ----
    __half2 Hd[4][4];
    {
        half8 efr = {0, 0, 0, 0, 0, 0, 0, 0};
        if (quad < 2) efr = *(const half8*)(efh + (size_t)me * 16 + quad * 8);
        f32x4 z4 = {0.f, 0.f, 0.f, 0.f};
#pragma unroll
        for (int pp = 0; pp < 4; ++pp) {
            half8 w1f = W8[(size_t)(wbase + pp) * 64 + lane];
            f32x4 hacc = __builtin_amdgcn_mfma_f32_16x16x32_f16(w1f, efr, z4, 0, 0, 0);
#pragma unroll
            for (int r = 0; r < 4; ++r)
                Hd[pp][r] = __float2half2_rn(__float2half(fmaxf(hacc[r], 0.f)));
        }
    }

    f32x4 acc0 = {0.f, 0.f, 0.f, 0.f}, acc1 = acc0, acc2 = acc0;
    f32x4 accP0 = acc0, accP1 = acc0, accP2 = acc0;

    // ---- loop1: fams 0,1,2 (K=256): A.h2[t] = Hd[pp][t] * (x[2kk],x[2kk+1]) ----
#pragma unroll
    for (int kk = 0; kk < 8; ++kk) {
        __half2 xp_ = x0p[kk], tp_ = t10p[kk];
        AF a0, a1, a2;
#pragma unroll
        for (int t = 0; t < 4; ++t) {
            a0.h2[t] = __hmul2(Hd[0][t], xp_);
            a1.h2[t] = __hmul2(Hd[1][t], xp_);
            a2.h2[t] = __hmul2(Hd[2][t], tp_);
        }
        half8 w0 = W8[(size_t)(wbase + 4 + kk) * 64 + lane];
        half8 w1f = W8[(size_t)(wbase + 12 + kk) * 64 + lane];
        half8 w2f = W8[(size_t)(wbase + 20 + kk) * 64 + lane];
        acc0 = __builtin_amdgcn_mfma_f32_16x16x32_f16(w0, a0.h8, acc0, 0, 0, 0);
        acc1 = __builtin_amdgcn_mfma_f32_16x16x32_f16(w1f, a1.h8, acc1, 0, 0, 0);
        acc2 = __builtin_amdgcn_mfma_f32_16x16x32_f16(w2f, a2.h8, acc2, 0, 0, 0);
    }

    // ---- loop2: fam3 (K=768), MFMA kk2=2kko+t covers if-pair u=kk2 ----
#pragma unroll
    for (int kko = 0; kko < 12; ++kko) {
        uint2 xu0 = *(const uint2*)&xw[m * 74 + 0 * 24 + 2 * kko];
        uint2 xu1 = *(const uint2*)&xw[m * 74 + 1 * 24 + 2 * kko];
        uint2 xu2 = *(const uint2*)&xw[m * 74 + 2 * 24 + 2 * kko];
        unsigned pv0[2] = {xu0.x, xu0.y};
        unsigned pv1[2] = {xu1.x, xu1.y};
        unsigned pv2[2] = {xu2.x, xu2.y};
#pragma unroll
        for (int t = 0; t < 2; ++t) {
            U32h2 u0, u1, u2;
            u0.u = pv0[t]; u1.u = pv1[t]; u2.u = pv2[t];
            AF a0, a1, a2;
#pragma unroll
            for (int r = 0; r < 4; ++r) {
                a0.h2[r] = __hmul2(Hd[3][r], u0.h);
                a1.h2[r] = __hmul2(Hd[3][r], u1.h);
                a2.h2[r] = __hmul2(Hd[3][r], u2.h);
            }
            half8 wf = W8[(size_t)(wbase + 28 + 2 * kko + t) * 64 + lane];
            accP0 = __builtin_amdgcn_mfma_f32_16x16x32_f16(wf, a0.h8, accP0, 0, 0, 0);
            accP1 = __builtin_amdgcn_mfma_f32_16x16x32_f16(wf, a1.h8, accP1, 0, 0, 0);
            accP2 = __builtin_amdgcn_mfma_f32_16x16x32_f16(wf, a2.h8, accP2, 0, 0, 0);
        }
    }

    // ---- epilogue: lane holds oo = quad*4+r for edge me ----
    float b00r = b00[me];
    float b01r0 = b01[(size_t)me * 3 + 0], b01r1 = b01[(size_t)me * 3 + 1],
          b01r2 = b01[(size_t)me * 3 + 2];
    float o0v[4], o1v[4][3];
#pragma unroll
    for (int r = 0; r < 4; ++r) {
        o0v[r] = b00r * acc0[r] + acc2[r];
        o1v[r][0] = b01r0 * acc1[r] + accP0[r];
        o1v[r][1] = b01r1 * acc1[r] + accP1[r];
        o1v[r][2] = b01r2 * acc1[r] + accP2[r];
    }
    int pos = pose[me];
    bool doStore = DO_Z ? (quad >= 2) : (quad < 2);
    if (doStore) {
        int qa = DO_Z ? (quad - 2) : quad;
        float* vp = vrow + (size_t)pos * 32;
        *(float4*)&vp[qa * 4] = make_float4(o0v[0], o0v[1], o0v[2], o0v[3]);
        float* p1 = vp + 8 + qa * 12;
        *(float4*)&p1[0] = make_float4(o1v[0][0], o1v[0][1], o1v[0][2], o1v[1][0]);
        *(float4*)&p1[4] = make_float4(o1v[1][1], o1v[1][2], o1v[2][0], o1v[2][1]);
        *(float4*)&p1[8] = make_float4(o1v[2][2], o1v[3][0], o1v[3][1], o1v[3][2]);
    }
    if (DO_Z && quad < 2) {
        int n = dst[me];
        float4 q0v = *(const float4*)&q0[(size_t)n * 8 + quad * 4];
        const float4* q1p = (const float4*)&q1[(size_t)n * 24 + quad * 12];
        float4 qa4 = q1p[0], qb4 = q1p[1], qc4 = q1p[2];
        float q1f[12] = {qa4.x, qa4.y, qa4.z, qa4.w, qb4.x, qb4.y, qb4.z, qb4.w,
                         qc4.x, qc4.y, qc4.z, qc4.w};
        float q0f[4] = {q0v.x, q0v.y, q0v.z, q0v.w};
        float zh0 = 0.f, zh1 = 0.f;
#pragma unroll
        for (int r = 0; r < 4; ++r) {
            float tt = q0f[r] * o0v[r] + q1f[r * 3 + 0] * o1v[r][0] +
                       q1f[r * 3 + 1] * o1v[r][1] + q1f[r * 3 + 2] * o1v[r][2];
            if (r < 2) zh0 += tt;
            else zh1 += tt;
        }
        const float scale = 0.35355339059327373f;  // 1/sqrt(8)
        *(float2*)&zb[(size_t)pos * 4 + quad * 2] = make_float2(zh0 * scale, zh1 * scale);
    }
}

// ---------------- q projection (layer 0 only) ----------------
__global__ void k_q(int N, const float* __restrict__ xs0, const float* __restrict__ xs1,
                    const float* __restrict__ wq,
                    float* __restrict__ q0, float* __restrict__ q1) {
    int t = blockIdx.x * 256 + threadIdx.x;
    if (t >= N * 32) return;
    int n = t >> 5, comp = t & 31;
    if (comp < 8) {
        float a = 0.f;
#pragma unroll
        for (int c = 0; c < 16; ++c) a += xs0[n * 16 + c] * wq[c * 8 + comp];
        q0[n * 8 + comp] = a;
    } else {
        int idx = comp - 8, dd = idx / 3, mm = idx % 3;
        float a = 0.f;
#pragma unroll
        for (int c = 0; c < 16; ++c) a += xs1[n * 48 + c * 3 + mm] * wq[128 + c * 8 + dd];
        q1[n * 24 + dd * 3 + mm] = a;
    }
}

// ---------------- per-node: softmax + aggregate + proj + SE3-norm (+next q) --
// 4 nodes per wave, 16 lanes per node; 16 nodes per block. CSR-ordered reads.
// Softmax sum fused into the accumulation pass (unnormalized exp, final 1/s).
__global__ __launch_bounds__(256) void k_attn(
    int N,
    const int* __restrict__ rowptr,
    const float* __restrict__ zb, const float* __restrict__ vrow,
    const float* __restrict__ wproj,  // (2,24,16)
    const float* __restrict__ gamma, const float* __restrict__ beta,  // (2,16)
    float* __restrict__ xs0, float* __restrict__ xs1,
    const float* __restrict__ wq_next,  // next layer wq (2,16,8) or nullptr
    float* __restrict__ q0, float* __restrict__ q1) {
    __shared__ float wpL[768];
    __shared__ float gL[32], btL[32];
    __shared__ float inb[16][100];   // per node: in0[24] + in1[72]
    __shared__ float aw[16][16][4];  // per node: alpha chunk (unnormalized)
    int tid = threadIdx.x;
    for (int i = tid; i < 768; i += 256) wpL[i] = wproj[i];
    if (tid < 32) { gL[tid] = gamma[tid]; btL[tid] = beta[tid]; }
    int wave = tid >> 6, lane = tid & 63;
    int sub = lane >> 4, l16 = lane & 15;
    int nodeIdx = wave * 4 + sub;
    int n = blockIdx.x * 16 + nodeIdx;
    if (n >= N) n = N - 1;
    int base = rowptr[n], deg = rowptr[n + 1] - base;
    const float4* zb4 = (const float4*)zb;

    // pass 1: per-head max (coalesced)
    float mx0 = -INFINITY, mx1 = -INFINITY, mx2 = -INFINITY, mx3 = -INFINITY;
    for (int j = l16; j < deg; j += 16) {
        float4 zv = zb4[base + j];
        mx0 = fmaxf(mx0, zv.x); mx1 = fmaxf(mx1, zv.y);
        mx2 = fmaxf(mx2, zv.z); mx3 = fmaxf(mx3, zv.w);
    }
#pragma unroll
    for (int off = 1; off < 16; off <<= 1) {
        mx0 = fmaxf(mx0, __shfl_xor(mx0, off));
        mx1 = fmaxf(mx1, __shfl_xor(mx1, off));
        mx2 = fmaxf(mx2, __shfl_xor(mx2, off));
        mx3 = fmaxf(mx3, __shfl_xor(mx3, off));
    }
    if (!isfinite(mx0)) mx0 = 0.f;
    if (!isfinite(mx1)) mx1 = 0.f;
    if (!isfinite(mx2)) mx2 = 0.f;
    if (!isfinite(mx3)) mx3 = 0.f;

    // pass 2 (merged): unnormalized alpha chunks -> LDS, accumulate + per-lane sums
    int c0 = 2 * l16, c1 = c0 + 1;
    int hA = ((c0 < 8) ? c0 : (c0 - 8) / 3) >> 1;
    int hB = ((c1 < 8) ? c1 : (c1 - 8) / 3) >> 1;
    float s0 = 0.f, s1 = 0.f, s2 = 0.f, s3 = 0.f;
    float accA = 0.f, accB = 0.f;
    for (int j0 = 0; j0 < deg; j0 += 16) {
        int j = j0 + l16;
        float4 a4 = make_float4(0.f, 0.f, 0.f, 0.f);
        if (j < deg) {
            float4 zv = zb4[base + j];
            a4.x = __expf(zv.x - mx0);
            a4.y = __expf(zv.y - mx1);
            a4.z = __expf(zv.z - mx2);
            a4.w = __expf(zv.w - mx3);
            s0 += a4.x; s1 += a4.y; s2 += a4.z; s3 += a4.w;
        }
        *(float4*)&aw[nodeIdx][l16][0] = a4;
        __builtin_amdgcn_wave_barrier();
        int cnt = min(16, deg - j0);
        const float* vbase = &vrow[(size_t)(base + j0) * 32 + c0];
        int jj = 0;
        for (; jj + 3 < cnt; jj += 4) {
            float2 v0 = *(const float2*)(vbase + (size_t)jj * 32);
            float2 v1 = *(const float2*)(vbase + (size_t)(jj + 1) * 32);
            float2 v2 = *(const float2*)(vbase + (size_t)(jj + 2) * 32);
            float2 v3 = *(const float2*)(vbase + (size_t)(jj + 3) * 32);
            accA += aw[nodeIdx][jj][hA] * v0.x + aw[nodeIdx][jj + 1][hA] * v1.x +
                    aw[nodeIdx][jj + 2][hA] * v2.x + aw[nodeIdx][jj + 3][hA] * v3.x;
            accB += aw[nodeIdx][jj][hB] * v0.y + aw[nodeIdx][jj + 1][hB] * v1.y +
                    aw[nodeIdx][jj + 2][hB] * v2.y + aw[nodeIdx][jj + 3][hB] * v3.y;
        }
        for (; jj < cnt; ++jj) {
            float2 v = *(const float2*)(vbase + (size_t)jj * 32);
            accA += aw[nodeIdx][jj][hA] * v.x;
            accB += aw[nodeIdx][jj][hB] * v.y;
        }
        __builtin_amdgcn_wave_barrier();
    }
#pragma unroll
    for (int off = 1; off < 16; off <<= 1) {
        s0 += __shfl_xor(s0, off); s1 += __shfl_xor(s1, off);
        s2 += __shfl_xor(s2, off); s3 += __shfl_xor(s3, off);
    }
    float inva[4] = {1.f / (s0 + 1e-9f), 1.f / (s1 + 1e-9f),
                     1.f / (s2 + 1e-9f), 1.f / (s3 + 1e-9f)};
    accA *= inva[hA];
    accB *= inva[hB];

    // stage concat([o, x]) into LDS
    float* in0 = inb[nodeIdx];
    float* in1 = in0 + 24;
    if (c0 < 8) { in0[c0] = accA; in0[c1] = accB; }
    else        { in1[c0 - 8] = accA; in1[c1 - 8] = accB; }
    in0[8 + l16] = xs0[(size_t)n * 16 + l16];
    {
        const float* xp = xs1 + (size_t)n * 48 + l16 * 3;
        in1[24 + l16 * 3 + 0] = xp[0];
        in1[24 + l16 * 3 + 1] = xp[1];
        in1[24 + l16 * 3 + 2] = xp[2];
    }
    __syncthreads();

    // projection: each lane -> 4 outputs of its node
    int c = l16;
    float y0 = 0.f;
#pragma unroll
    for (int j = 0; j < 24; ++j) y0 += in0[j] * wpL[j * 16 + c];
    float y1v[3];
#pragma unroll
    for (int mm = 0; mm < 3; ++mm) {
        float y = 0.f;
#pragma unroll
        for (int j = 0; j < 24; ++j) y += in1[j * 3 + mm] * wpL[384 + j * 16 + c];
        y1v[mm] = y;
    }
    float n0 = sqrtf(y0 * y0 + 1e-12f);
    float n1 = sqrtf(y1v[0] * y1v[0] + y1v[1] * y1v[1] + y1v[2] * y1v[2] + 1e-12f);
    float mu0 = n0, mu1 = n1;
#pragma unroll
    for (int off = 1; off < 16; off <<= 1) {
        mu0 += __shfl_xor(mu0, off);
        mu1 += __shfl_xor(mu1, off);
    }
    mu0 *= 0.0625f; mu1 *= 0.0625f;
    float dv0 = n0 - mu0, dv1 = n1 - mu1;
    float var0 = dv0 * dv0, var1 = dv1 * dv1;
#pragma unroll
    for (int off = 1; off < 16; off <<= 1) {
        var0 += __shfl_xor(var0, off);
        var1 += __shfl_xor(var1, off);
    }
    var0 *= 0.0625f; var1 *= 0.0625f;
    float ln0 = dv0 * rsqrtf(var0 + 1e-5f) * gL[c] + btL[c];
    float ln1 = dv1 * rsqrtf(var1 + 1e-5f) * gL[16 + c] + btL[16 + c];
    float fac0 = fmaxf(ln0, 0.f) / (n0 + 1e-3f);
    float fac1 = fmaxf(ln1, 0.f) / (n1 + 1e-3f);
    float x0n = y0 * fac0;
    float x1n[3] = {y1v[0] * fac1, y1v[1] * fac1, y1v[2] * fac1};
    xs0[(size_t)n * 16 + c] = x0n;
    float* xo = xs1 + (size_t)n * 48 + c * 3;
    xo[0] = x1n[0]; xo[1] = x1n[1]; xo[2] = x1n[2];

    // ---- fused next-layer q ----
    if (wq_next) {
        __builtin_amdgcn_wave_barrier();
        in0[8 + c] = x0n;
        in1[24 + c * 3 + 0] = x1n[0];
        in1[24 + c * 3 + 1] = x1n[1];
        in1[24 + c * 3 + 2] = x1n[2];
        __builtin_amdgcn_wave_barrier();
        int compA = 2 * l16, compB = compA + 1;
#pragma unroll
        for (int cb = 0; cb < 2; ++cb) {
            int comp = cb ? compB : compA;
            float a = 0.f;
            if (comp < 8) {
#pragma unroll
                for (int cc = 0; cc < 16; ++cc)
                    a += in0[8 + cc] * wq_next[cc * 8 + comp];
                q0[(size_t)n * 8 + comp] = a;
            } else {
                int idx = comp - 8, dd = idx / 3, mm = idx % 3;
#pragma unroll
                for (int cc = 0; cc < 16; ++cc)
                    a += in1[24 + cc * 3 + mm] * wq_next[128 + cc * 8 + dd];
                q1[(size_t)n * 24 + idx] = a;
            }
        }
    }
}

// ---------------- final output: segment-sum(vrow) + x @ wself ----------------
__global__ __launch_bounds__(256) void k_out(
    int N,
    const int* __restrict__ rowptr, const float* __restrict__ vrow,
    const float* __restrict__ xs0, const float* __restrict__ xs1,
    const float* __restrict__ wself,  // (2,16,8)
    float* __restrict__ out) {
    int tid = threadIdx.x;
    int wave = tid >> 6, lane = tid & 63;
    int sub = lane >> 4, l16 = lane & 15;
    int n = blockIdx.x * 16 + wave * 4 + sub;
    if (n >= N) n = N - 1;
    int base = rowptr[n], deg = rowptr[n + 1] - base;

    int c0 = 2 * l16, c1 = c0 + 1;
    float accA = 0.f, accB = 0.f;
    const float* vbase = &vrow[(size_t)base * 32 + c0];
    int j = 0;
    for (; j + 3 < deg; j += 4) {
        float2 v0 = *(const float2*)(vbase + (size_t)j * 32);
        float2 v1 = *(const float2*)(vbase + (size_t)(j + 1) * 32);
        float2 v2 = *(const float2*)(vbase + (size_t)(j + 2) * 32);
        float2 v3 = *(const float2*)(vbase + (size_t)(j + 3) * 32);
        accA += v0.x + v1.x + v2.x + v3.x;
        accB += v0.y + v1.y + v2.y + v3.y;
    }
    for (; j < deg; ++j) {
        float2 v = *(const float2*)(vbase + (size_t)j * 32);
        accA += v.x;
        accB += v.y;
    }
    if (c0 < 8) {
#pragma unroll
        for (int c = 0; c < 16; ++c) {
            float xv = xs0[(size_t)n * 16 + c];
            accA += xv * wself[c * 8 + c0];
            accB += xv * wself[c * 8 + c1];
        }
    } else {
        int dA = (c0 - 8) / 3, mA = (c0 - 8) % 3;
        int dB = (c1 - 8) / 3, mB = (c1 - 8) % 3;
#pragma unroll
        for (int c = 0; c < 16; ++c) {
            accA += xs1[(size_t)n * 48 + c * 3 + mA] * wself[128 + c * 8 + dA];
            accB += xs1[(size_t)n * 48 + c * 3 + mB] * wself[128 + c * 8 + dB];
        }
    }
    *(float2*)&out[(size_t)n * 32 + c0] = make_float2(accA, accB);
}

// ---------------------------------------------------------------------------
extern "C" void kernel_launch(void* const* d_in, const int* in_sizes, int n_in,
                              void* d_out, int out_size, void* d_ws, size_t ws_size,
                              hipStream_t stream) {
    const float* x0 = (const float*)d_in[0];
    const float* x1 = (const float*)d_in[1];
    const float* ef = (const float*)d_in[2];
    const float* b00 = (const float*)d_in[3];
    const float* b01 = (const float*)d_in[4];
    const float* b10 = (const float*)d_in[5];
    const float* b11 = (const float*)d_in[6];
    const float* kvw1 = (const float*)d_in[7];    // (2,4,16,16)
    const float* kvw2n = (const float*)d_in[8];   // (2,3,16,16,16)
    const float* kvw211 = (const float*)d_in[9];  // (2,16,16,16,3)
    const float* wq = (const float*)d_in[10];     // (2,2,16,8)
    const float* wproj = (const float*)d_in[11];  // (2,2,24,16)
    const float* gam = (const float*)d_in[12];    // (2,2,16)
    const float* bet = (const float*)d_in[13];
    const float* fcw1 = (const float*)d_in[14];    // (4,16,16)
    const float* fcw2n = (const float*)d_in[15];   // (3,16,8,16)
    const float* fcw211 = (const float*)d_in[16];  // (16,8,16,3)
    const float* fcself = (const float*)d_in[17];  // (2,16,8)
    const int* esrc = (const int*)d_in[18];
    const int* edst = (const int*)d_in[19];
    int N = in_sizes[0] / 16;
    int E = in_sizes[18];
    float* out = (float*)d_out;

    float* ws = (float*)d_ws;
    size_t off = 0;
    float* xs0 = ws + off; off += (size_t)N * 16;
    float* xs1 = ws + off; off += (size_t)N * 48;
    float* q0b = ws + off; off += (size_t)N * 8;
    float* q1b = ws + off; off += (size_t)N * 24;
    float* vrow = ws + off; off += (size_t)E * 32;
    float* zb = ws + off; off += (size_t)E * 4;
    int* counts = (int*)(ws + off); off += N;
    int* rowptr = (int*)(ws + off); off += N + 1;
    int* cursor = (int*)(ws + off); off += N;
    int* pose = (int*)(ws + off); off += E;
    off = (off + 3) & ~(size_t)3;
    unsigned short* efh = (unsigned short*)(ws + off); off += (size_t)E * 16 / 2;
    unsigned short* Wfrag = (unsigned short*)(ws + off); off += (size_t)156 * 64 * 8 / 2;

    const int tpb = 256;
    int ebl = (E + 255) / 256;
    int cblk = (E / 16 + 3) / 4;
    int nbl16 = (N + 15) / 16;

    k_prepw<<<(156 * 512 + 255) / 256, tpb, 0, stream>>>(kvw1, fcw1, kvw2n, kvw211,
                                                         fcw2n, fcw211, Wfrag);
    int mtot = N * 64 + E * 16;
    k_misc<<<(mtot + 255) / 256, tpb, 0, stream>>>(x0, x1, ef, xs0, xs1, efh,
                                                   N * 16, N * 48, E * 16);
    hipMemsetAsync(counts, 0, (size_t)N * 4, stream);
    k_hist<<<ebl, tpb, 0, stream>>>(edst, counts, E);
    int CH = (N + 1023) / 1024;
    k_scan<<<1, 1024, 0, stream>>>(counts, rowptr, cursor, N, CH);
    k_scatter<<<ebl, tpb, 0, stream>>>(edst, cursor, pose, E);
    k_q<<<(N * 32 + 255) / 256, tpb, 0, stream>>>(N, xs0, xs1, wq, q0b, q1b);

    // layer 0
    k_conv<16, true><<<cblk, tpb, 0, stream>>>(E, esrc, edst, pose, xs0, xs1,
                                               b00, b01, b10, b11, efh, Wfrag, 0,
                                               q0b, q1b, vrow, zb);
    k_attn<<<nbl16, tpb, 0, stream>>>(N, rowptr, zb, vrow, wproj,
                                      gam, bet, xs0, xs1, wq + 256, q0b, q1b);
    // layer 1
    k_conv<16, true><<<cblk, tpb, 0, stream>>>(E, esrc, edst, pose, xs0, xs1,
                                               b00, b01, b10, b11, efh, Wfrag, 52,
                                               q0b, q1b, vrow, zb);
    k_attn<<<nbl16, tpb, 0, stream>>>(N, rowptr, zb, vrow, wproj + 768,
                                      gam + 32, bet + 32, xs0, xs1, nullptr, q0b, q1b);
    // final conv + output
    k_conv<8, false><<<cblk, tpb, 0, stream>>>(E, esrc, edst, pose, xs0, xs1,
                                               b00, b01, b10, b11, efh, Wfrag, 104,
                                               q0b, q1b, vrow, zb);
    k_out<<<nbl16, tpb, 0, stream>>>(N, rowptr, vrow, xs0, xs1, fcself, out);
}

// Round 11
// 299.046 us; speedup vs baseline: 1.0032x; 1.0032x over previous
//
#include <hip/hip_runtime.h>
#include <hip/hip_fp16.h>
#include <math.h>

// ---------------------------------------------------------------------------
// EquivariantNet forward — round 11.
// r7/r10 lineage (known good): plain launch_bounds(256) conv + r10's merged
// softmax-sum attn. New: (1) b11 staged through LDS via 7 coalesced loads/lane
// (replaces 27 per-lane L2-latency loads), (2) prepw+misc+q fused into one
// range-split k_init (13 -> 11 launches).
// Shapes: N=8192, E=131072, C=16, mid=16, KV=16, ckv=8, Co=8, HEADS=4, L=2
// ---------------------------------------------------------------------------

typedef _Float16 half8 __attribute__((ext_vector_type(8)));
typedef float f32x4 __attribute__((ext_vector_type(4)));

union AF {
    half8 h8;
    __half2 h2[4];
};
union U32h2 {
    unsigned u;
    __half2 h;
};

// ---------------- CSR build over edge_dst ----------------
__global__ void k_hist(const int* __restrict__ dst, int* __restrict__ counts, int E) {
    int e = blockIdx.x * 256 + threadIdx.x;
    if (e < E) atomicAdd(&counts[dst[e]], 1);
}

__global__ __launch_bounds__(1024) void k_scan(const int* __restrict__ counts,
                                               int* __restrict__ rowptr,
                                               int* __restrict__ cursor,
                                               int N, int CH) {
    __shared__ int part[1024];
    int t = threadIdx.x;
    int s = 0;
    for (int i = 0; i < CH; ++i) {
        int idx = t * CH + i;
        if (idx < N) s += counts[idx];
    }
    part[t] = s;
    __syncthreads();
    for (int off = 1; off < 1024; off <<= 1) {
        int v = (t >= off) ? part[t - off] : 0;
        __syncthreads();
        part[t] += v;
        __syncthreads();
    }
    int run = (t == 0) ? 0 : part[t - 1];
    for (int i = 0; i < CH; ++i) {
        int idx = t * CH + i;
        if (idx < N) {
            rowptr[idx] = run;
            cursor[idx] = run;
            run += counts[idx];
        }
    }
    if (t == 0) rowptr[N] = part[1023];
}

__global__ void k_scatter(const int* __restrict__ dst, int* __restrict__ cursor,
                          int* __restrict__ pose, int E) {
    int e = blockIdx.x * 256 + threadIdx.x;
    if (e < E) {
        int pos = atomicAdd(&cursor[dst[e]], 1);
        pose[e] = pos;
    }
}

// ---------------- fused init: W-frag permute + xs copies + ef->f16 + layer0 q
// ranges: [0,79872) prepw | xs0 copy | xs1 copy | efh | q-projection
__global__ void k_init(const float* __restrict__ x0, const float* __restrict__ x1,
                       const float* __restrict__ ef,
                       const float* __restrict__ kvw1, const float* __restrict__ fcw1,
                       const float* __restrict__ kvw2n, const float* __restrict__ kvw211,
                       const float* __restrict__ fcw2n, const float* __restrict__ fcw211,
                       const float* __restrict__ wq,
                       float* __restrict__ xs0, float* __restrict__ xs1,
                       unsigned short* __restrict__ efh,
                       unsigned short* __restrict__ Wfrag,
                       float* __restrict__ q0, float* __restrict__ q1,
                       int N, int E) {
    int i = blockIdx.x * 256 + threadIdx.x;
    if (i < 156 * 64 * 8) {
        int t = i;
        int j = t & 7;
        int lane = (t >> 3) & 63;
        int row = t >> 9;
        int quad = lane >> 4, m = lane & 15;
        int c = row / 52, r = row % 52;
        int KVO = (c < 2) ? 16 : 8;
        const float* w1src = (c < 2) ? (kvw1 + c * 1024) : fcw1;
        const float* w2n = (c < 2) ? (kvw2n + c * 12288) : fcw2n;
        const float* w211 = (c < 2) ? (kvw211 + c * 12288) : fcw211;
        float v = 0.f;
        if (r < 4) {
            if (quad < 2) v = w1src[r * 256 + (quad * 8 + j) * 16 + m];
        } else if (r < 28) {
            int fam = (r - 4) >> 3, kk = (r - 4) & 7;
            int h = quad * 4 + ((j >> 1) & 3), ii = 2 * kk + (j & 1);
            if (m < KVO) v = w2n[((fam * 16 + h) * KVO + m) * 16 + ii];
        } else {
            int kk2 = r - 28;
            int h = quad * 4 + ((j >> 1) & 3);
            int ifx = 2 * kk2 + (j & 1);
            int ii = ifx / 3, f = ifx % 3;
            if (m < KVO) v = w211[((h * KVO + m) * 16 + ii) * 3 + f];
        }
        Wfrag[t] = __half_as_ushort(__float2half(v));
        return;
    }
    i -= 156 * 64 * 8;
    if (i < N * 16) { xs0[i] = x0[i]; return; }
    i -= N * 16;
    if (i < N * 48) { xs1[i] = x1[i]; return; }
    i -= N * 48;
    if (i < E * 16) { efh[i] = __half_as_ushort(__float2half(ef[i])); return; }
    i -= E * 16;
    if (i < N * 32) {
        int n = i >> 5, comp = i & 31;
        if (comp < 8) {
            float a = 0.f;
#pragma unroll
            for (int c = 0; c < 16; ++c) a += x0[n * 16 + c] * wq[c * 8 + comp];
            q0[n * 8 + comp] = a;
        } else {
            int idx = comp - 8, dd = idx / 3, mm = idx % 3;
            float a = 0.f;
#pragma unroll
            for (int c = 0; c < 16; ++c) a += x1[n * 48 + c * 3 + mm] * wq[128 + c * 8 + dd];
            q1[n * 24 + dd * 3 + mm] = a;
        }
    }
}

// ---------------- fused MFMA conv (+H, +z), f16, pair-shared-H builds --------
// vrow[pos][32]: [0..8) scalar d | [8..32) 8+d*3+m.  zb[pos][4]: per-head z.
// LDS: xB pairs [wave][m][p*24+u] stride 74; b11 staged [wave][e][k] stride 29.
template <int KVO, bool DO_Z>
__global__ __launch_bounds__(256) void k_conv(
    int E,
    const int* __restrict__ src, const int* __restrict__ dst,
    const int* __restrict__ pose,
    const float* __restrict__ xs0, const float* __restrict__ xs1,
    const float* __restrict__ b00, const float* __restrict__ b01,
    const float* __restrict__ b10, const float* __restrict__ b11,
    const unsigned short* __restrict__ efh,    // (E,16) f16
    const unsigned short* __restrict__ Wfrag,  // frag-ordered weights (f16)
    int wbase,
    const float* __restrict__ q0, const float* __restrict__ q1,
    float* __restrict__ vrow, float* __restrict__ zb)
{
    __shared__ __align__(16) unsigned xBL[4][16 * 74];
    __shared__ float b11L[4][16 * 29];
    int tid = threadIdx.x;
    int wave = tid >> 6, lane = tid & 63;
    int tile = blockIdx.x * 4 + wave;
    if (tile * 16 >= E) return;
    int m = lane & 15, quad = lane >> 4;
    int e0 = tile * 16;
    int me = e0 + m;
    int s = src[me];
    unsigned* xw = xBL[wave];
    const half8* W8 = (const half8*)Wfrag;

    // ---- phase A: cooperative coalesced b11 stage (16 edges x 27 = 432 dwords)
    {
        const float* gb = b11 + (size_t)e0 * 27;
        float* lb = b11L[wave];
#pragma unroll
        for (int it = 0; it < 7; ++it) {
            int d = it * 64 + lane;
            if (d < 432) {
                int ee = d / 27, kk = d - ee * 27;
                lb[ee * 29 + kk] = gb[d];
            }
        }
    }
    __syncthreads();

    // ---- phase B: xB[p][if] = sum_q x1[i][q]*b11[p][q][f]; quad covers if [quad*12,+12)
    {
        float x1c[12];
        const float4* xp = (const float4*)(xs1 + (size_t)s * 48 + quad * 12);
#pragma unroll
        for (int cc = 0; cc < 3; ++cc) {
            float4 v = xp[cc];
            x1c[cc * 4 + 0] = v.x; x1c[cc * 4 + 1] = v.y;
            x1c[cc * 4 + 2] = v.z; x1c[cc * 4 + 3] = v.w;
        }
        const float* lb = &b11L[wave][m * 29];
        float b11r[27];
#pragma unroll
        for (int k = 0; k < 27; ++k) b11r[k] = lb[k];
#pragma unroll
        for (int p = 0; p < 3; ++p) {
            float vals[12];
#pragma unroll
            for (int i2 = 0; i2 < 4; ++i2) {
#pragma unroll
                for (int f = 0; f < 3; ++f) {
                    float a = 0.f;
#pragma unroll
                    for (int q = 0; q < 3; ++q) a += x1c[i2 * 3 + q] * b11r[p * 9 + q * 3 + f];
                    vals[i2 * 3 + f] = a;
                }
            }
            unsigned uu[6];
#pragma unroll
            for (int u = 0; u < 6; ++u) {
                U32h2 w;
                w.h = __float22half2_rn(make_float2(vals[2 * u], vals[2 * u + 1]));
                uu[u] = w.u;
            }
            int boff = m * 74 + p * 24 + quad * 6;
            *(uint2*)&xw[boff + 0] = make_uint2(uu[0], uu[1]);
            *(uint2*)&xw[boff + 2] = make_uint2(uu[2], uu[3]);
            *(uint2*)&xw[boff + 4] = make_uint2(uu[4], uu[5]);
        }
    }
    __syncthreads();

    // ---- x0 / t10 rows as natural half2 pairs (8 regs each) ----
    __half2 x0p[8], t10p[8];
    {
        const float4* p = (const float4*)(xs0 + (size_t)s * 16);
#pragma unroll
        for (int k = 0; k < 4; ++k) {
            float4 v = p[k];
            x0p[2 * k + 0] = __float22half2_rn(make_float2(v.x, v.y));
            x0p[2 * k + 1] = __float22half2_rn(make_float2(v.z, v.w));
        }
        float bq0 = b10[(size_t)me * 3 + 0], bq1 = b10[(size_t)me * 3 + 1],
              bq2 = b10[(size_t)me * 3 + 2];
        const float4* xp = (const float4*)(xs1 + (size_t)s * 48);
        float tf[16];
#pragma unroll
        for (int g = 0; g < 4; ++g) {
            float4 a = xp[g * 3 + 0], b = xp[g * 3 + 1], cc = xp[g * 3 + 2];
            float xf[12] = {a.x, a.y, a.z, a.w, b.x, b.y, b.z, b.w, cc.x, cc.y, cc.z, cc.w};
#pragma unroll
            for (int i2 = 0; i2 < 4; ++i2)
                tf[g * 4 + i2] = bq0 * xf[i2 * 3] + bq1 * xf[i2 * 3 + 1] + bq2 * xf[i2 * 3 + 2];
        }
#pragma unroll
        for (int k = 0; k < 8; ++k)
            t10p[k] = __float22half2_rn(make_float2(tf[2 * k], tf[2 * k + 1]));
    }

    // ---- H via 4 f16 MFMAs -> dup-half2 per (pp, t): H[pp][h=quad*4+t] ----
    __half2 Hd[4][4];
    {
        half8 efr = {0, 0, 0, 0, 0, 0, 0, 0};
        if (quad < 2) efr = *(const half8*)(efh + (size_t)me * 16 + quad * 8);
        f32x4 z4 = {0.f, 0.f, 0.f, 0.f};
#pragma unroll
        for (int pp = 0; pp < 4; ++pp) {
            half8 w1f = W8[(size_t)(wbase + pp) * 64 + lane];
            f32x4 hacc = __builtin_amdgcn_mfma_f32_16x16x32_f16(w1f, efr, z4, 0, 0, 0);
#pragma unroll
            for (int r = 0; r < 4; ++r)
                Hd[pp][r] = __float2half2_rn(__float2half(fmaxf(hacc[r], 0.f)));
        }
    }

    f32x4 acc0 = {0.f, 0.f, 0.f, 0.f}, acc1 = acc0, acc2 = acc0;
    f32x4 accP0 = acc0, accP1 = acc0, accP2 = acc0;

    // ---- loop1: fams 0,1,2 (K=256): A.h2[t] = Hd[pp][t] * (x[2kk],x[2kk+1]) ----
#pragma unroll
    for (int kk = 0; kk < 8; ++kk) {
        __half2 xp_ = x0p[kk], tp_ = t10p[kk];
        AF a0, a1, a2;
#pragma unroll
        for (int t = 0; t < 4; ++t) {
            a0.h2[t] = __hmul2(Hd[0][t], xp_);
            a1.h2[t] = __hmul2(Hd[1][t], xp_);
            a2.h2[t] = __hmul2(Hd[2][t], tp_);
        }
        half8 w0 = W8[(size_t)(wbase + 4 + kk) * 64 + lane];
        half8 w1f = W8[(size_t)(wbase + 12 + kk) * 64 + lane];
        half8 w2f = W8[(size_t)(wbase + 20 + kk) * 64 + lane];
        acc0 = __builtin_amdgcn_mfma_f32_16x16x32_f16(w0, a0.h8, acc0, 0, 0, 0);
        acc1 = __builtin_amdgcn_mfma_f32_16x16x32_f16(w1f, a1.h8, acc1, 0, 0, 0);
        acc2 = __builtin_amdgcn_mfma_f32_16x16x32_f16(w2f, a2.h8, acc2, 0, 0, 0);
    }

    // ---- loop2: fam3 (K=768), MFMA kk2=2kko+t covers if-pair u=kk2 ----
#pragma unroll
    for (int kko = 0; kko < 12; ++kko) {
        uint2 xu0 = *(const uint2*)&xw[m * 74 + 0 * 24 + 2 * kko];
        uint2 xu1 = *(const uint2*)&xw[m * 74 + 1 * 24 + 2 * kko];
        uint2 xu2 = *(const uint2*)&xw[m * 74 + 2 * 24 + 2 * kko];
        unsigned pv0[2] = {xu0.x, xu0.y};
        unsigned pv1[2] = {xu1.x, xu1.y};
        unsigned pv2[2] = {xu2.x, xu2.y};
#pragma unroll
        for (int t = 0; t < 2; ++t) {
            U32h2 u0, u1, u2;
            u0.u = pv0[t]; u1.u = pv1[t]; u2.u = pv2[t];
            AF a0, a1, a2;
#pragma unroll
            for (int r = 0; r < 4; ++r) {
                a0.h2[r] = __hmul2(Hd[3][r], u0.h);
                a1.h2[r] = __hmul2(Hd[3][r], u1.h);
                a2.h2[r] = __hmul2(Hd[3][r], u2.h);
            }
            half8 wf = W8[(size_t)(wbase + 28 + 2 * kko + t) * 64 + lane];
            accP0 = __builtin_amdgcn_mfma_f32_16x16x32_f16(wf, a0.h8, accP0, 0, 0, 0);
            accP1 = __builtin_amdgcn_mfma_f32_16x16x32_f16(wf, a1.h8, accP1, 0, 0, 0);
            accP2 = __builtin_amdgcn_mfma_f32_16x16x32_f16(wf, a2.h8, accP2, 0, 0, 0);
        }
    }

    // ---- epilogue: lane holds oo = quad*4+r for edge me ----
    float b00r = b00[me];
    float b01r0 = b01[(size_t)me * 3 + 0], b01r1 = b01[(size_t)me * 3 + 1],
          b01r2 = b01[(size_t)me * 3 + 2];
    float o0v[4], o1v[4][3];
#pragma unroll
    for (int r = 0; r < 4; ++r) {
        o0v[r] = b00r * acc0[r] + acc2[r];
        o1v[r][0] = b01r0 * acc1[r] + accP0[r];
        o1v[r][1] = b01r1 * acc1[r] + accP1[r];
        o1v[r][2] = b01r2 * acc1[r] + accP2[r];
    }
    int pos = pose[me];
    bool doStore = DO_Z ? (quad >= 2) : (quad < 2);
    if (doStore) {
        int qa = DO_Z ? (quad - 2) : quad;
        float* vp = vrow + (size_t)pos * 32;
        *(float4*)&vp[qa * 4] = make_float4(o0v[0], o0v[1], o0v[2], o0v[3]);
        float* p1 = vp + 8 + qa * 12;
        *(float4*)&p1[0] = make_float4(o1v[0][0], o1v[0][1], o1v[0][2], o1v[1][0]);
        *(float4*)&p1[4] = make_float4(o1v[1][1], o1v[1][2], o1v[2][0], o1v[2][1]);
        *(float4*)&p1[8] = make_float4(o1v[2][2], o1v[3][0], o1v[3][1], o1v[3][2]);
    }
    if (DO_Z && quad < 2) {
        int n = dst[me];
        float4 q0v = *(const float4*)&q0[(size_t)n * 8 + quad * 4];
        const float4* q1p = (const float4*)&q1[(size_t)n * 24 + quad * 12];
        float4 qa4 = q1p[0], qb4 = q1p[1], qc4 = q1p[2];
        float q1f[12] = {qa4.x, qa4.y, qa4.z, qa4.w, qb4.x, qb4.y, qb4.z, qb4.w,
                         qc4.x, qc4.y, qc4.z, qc4.w};
        float q0f[4] = {q0v.x, q0v.y, q0v.z, q0v.w};
        float zh0 = 0.f, zh1 = 0.f;
#pragma unroll
        for (int r = 0; r < 4; ++r) {
            float tt = q0f[r] * o0v[r] + q1f[r * 3 + 0] * o1v[r][0] +
                       q1f[r * 3 + 1] * o1v[r][1] + q1f[r * 3 + 2] * o1v[r][2];
            if (r < 2) zh0 += tt;
            else zh1 += tt;
        }
        const float scale = 0.35355339059327373f;  // 1/sqrt(8)
        *(float2*)&zb[(size_t)pos * 4 + quad * 2] = make_float2(zh0 * scale, zh1 * scale);
    }
}

// ---------------- per-node: softmax + aggregate + proj + SE3-norm (+next q) --
// 4 nodes per wave, 16 lanes per node; 16 nodes per block. CSR-ordered reads.
// Softmax sum fused into the accumulation pass (unnormalized exp, final 1/s).
__global__ __launch_bounds__(256) void k_attn(
    int N,
    const int* __restrict__ rowptr,
    const float* __restrict__ zb, const float* __restrict__ vrow,
    const float* __restrict__ wproj,  // (2,24,16)
    const float* __restrict__ gamma, const float* __restrict__ beta,  // (2,16)
    float* __restrict__ xs0, float* __restrict__ xs1,
    const float* __restrict__ wq_next,  // next layer wq (2,16,8) or nullptr
    float* __restrict__ q0, float* __restrict__ q1) {
    __shared__ float wpL[768];
    __shared__ float gL[32], btL[32];
    __shared__ float inb[16][100];   // per node: in0[24] + in1[72]
    __shared__ float aw[16][16][4];  // per node: alpha chunk (unnormalized)
    int tid = threadIdx.x;
    for (int i = tid; i < 768; i += 256) wpL[i] = wproj[i];
    if (tid < 32) { gL[tid] = gamma[tid]; btL[tid] = beta[tid]; }
    int wave = tid >> 6, lane = tid & 63;
    int sub = lane >> 4, l16 = lane & 15;
    int nodeIdx = wave * 4 + sub;
    int n = blockIdx.x * 16 + nodeIdx;
    if (n >= N) n = N - 1;
    int base = rowptr[n], deg = rowptr[n + 1] - base;
    const float4* zb4 = (const float4*)zb;

    // pass 1: per-head max (coalesced)
    float mx0 = -INFINITY, mx1 = -INFINITY, mx2 = -INFINITY, mx3 = -INFINITY;
    for (int j = l16; j < deg; j += 16) {
        float4 zv = zb4[base + j];
        mx0 = fmaxf(mx0, zv.x); mx1 = fmaxf(mx1, zv.y);
        mx2 = fmaxf(mx2, zv.z); mx3 = fmaxf(mx3, zv.w);
    }
#pragma unroll
    for (int off = 1; off < 16; off <<= 1) {
        mx0 = fmaxf(mx0, __shfl_xor(mx0, off));
        mx1 = fmaxf(mx1, __shfl_xor(mx1, off));
        mx2 = fmaxf(mx2, __shfl_xor(mx2, off));
        mx3 = fmaxf(mx3, __shfl_xor(mx3, off));
    }
    if (!isfinite(mx0)) mx0 = 0.f;
    if (!isfinite(mx1)) mx1 = 0.f;
    if (!isfinite(mx2)) mx2 = 0.f;
    if (!isfinite(mx3)) mx3 = 0.f;

    // pass 2 (merged): unnormalized alpha chunks -> LDS, accumulate + per-lane sums
    int c0 = 2 * l16, c1 = c0 + 1;
    int hA = ((c0 < 8) ? c0 : (c0 - 8) / 3) >> 1;
    int hB = ((c1 < 8) ? c1 : (c1 - 8) / 3) >> 1;
    float s0 = 0.f, s1 = 0.f, s2 = 0.f, s3 = 0.f;
    float accA = 0.f, accB = 0.f;
    for (int j0 = 0; j0 < deg; j0 += 16) {
        int j = j0 + l16;
        float4 a4 = make_float4(0.f, 0.f, 0.f, 0.f);
        if (j < deg) {
            float4 zv = zb4[base + j];
            a4.x = __expf(zv.x - mx0);
            a4.y = __expf(zv.y - mx1);
            a4.z = __expf(zv.z - mx2);
            a4.w = __expf(zv.w - mx3);
            s0 += a4.x; s1 += a4.y; s2 += a4.z; s3 += a4.w;
        }
        *(float4*)&aw[nodeIdx][l16][0] = a4;
        __builtin_amdgcn_wave_barrier();
        int cnt = min(16, deg - j0);
        const float* vbase = &vrow[(size_t)(base + j0) * 32 + c0];
        int jj = 0;
        for (; jj + 3 < cnt; jj += 4) {
            float2 v0 = *(const float2*)(vbase + (size_t)jj * 32);
            float2 v1 = *(const float2*)(vbase + (size_t)(jj + 1) * 32);
            float2 v2 = *(const float2*)(vbase + (size_t)(jj + 2) * 32);
            float2 v3 = *(const float2*)(vbase + (size_t)(jj + 3) * 32);
            accA += aw[nodeIdx][jj][hA] * v0.x + aw[nodeIdx][jj + 1][hA] * v1.x +
                    aw[nodeIdx][jj + 2][hA] * v2.x + aw[nodeIdx][jj + 3][hA] * v3.x;
            accB += aw[nodeIdx][jj][hB] * v0.y + aw[nodeIdx][jj + 1][hB] * v1.y +
                    aw[nodeIdx][jj + 2][hB] * v2.y + aw[nodeIdx][jj + 3][hB] * v3.y;
        }
        for (; jj < cnt; ++jj) {
            float2 v = *(const float2*)(vbase + (size_t)jj * 32);
            accA += aw[nodeIdx][jj][hA] * v.x;
            accB += aw[nodeIdx][jj][hB] * v.y;
        }
        __builtin_amdgcn_wave_barrier();
    }
#pragma unroll
    for (int off = 1; off < 16; off <<= 1) {
        s0 += __shfl_xor(s0, off); s1 += __shfl_xor(s1, off);
        s2 += __shfl_xor(s2, off); s3 += __shfl_xor(s3, off);
    }
    float inva[4] = {1.f / (s0 + 1e-9f), 1.f / (s1 + 1e-9f),
                     1.f / (s2 + 1e-9f), 1.f / (s3 + 1e-9f)};
    accA *= inva[hA];
    accB *= inva[hB];

    // stage concat([o, x]) into LDS
    float* in0 = inb[nodeIdx];
    float* in1 = in0 + 24;
    if (c0 < 8) { in0[c0] = accA; in0[c1] = accB; }
    else        { in1[c0 - 8] = accA; in1[c1 - 8] = accB; }
    in0[8 + l16] = xs0[(size_t)n * 16 + l16];
    {
        const float* xp = xs1 + (size_t)n * 48 + l16 * 3;
        in1[24 + l16 * 3 + 0] = xp[0];
        in1[24 + l16 * 3 + 1] = xp[1];
        in1[24 + l16 * 3 + 2] = xp[2];
    }
    __syncthreads();

    // projection: each lane -> 4 outputs of its node
    int c = l16;
    float y0 = 0.f;
#pragma unroll
    for (int j = 0; j < 24; ++j) y0 += in0[j] * wpL[j * 16 + c];
    float y1v[3];
#pragma unroll
    for (int mm = 0; mm < 3; ++mm) {
        float y = 0.f;
#pragma unroll
        for (int j = 0; j < 24; ++j) y += in1[j * 3 + mm] * wpL[384 + j * 16 + c];
        y1v[mm] = y;
    }
    float n0 = sqrtf(y0 * y0 + 1e-12f);
    float n1 = sqrtf(y1v[0] * y1v[0] + y1v[1] * y1v[1] + y1v[2] * y1v[2] + 1e-12f);
    float mu0 = n0, mu1 = n1;
#pragma unroll
    for (int off = 1; off < 16; off <<= 1) {
        mu0 += __shfl_xor(mu0, off);
        mu1 += __shfl_xor(mu1, off);
    }
    mu0 *= 0.0625f; mu1 *= 0.0625f;
    float dv0 = n0 - mu0, dv1 = n1 - mu1;
    float var0 = dv0 * dv0, var1 = dv1 * dv1;
#pragma unroll
    for (int off = 1; off < 16; off <<= 1) {
        var0 += __shfl_xor(var0, off);
        var1 += __shfl_xor(var1, off);
    }
    var0 *= 0.0625f; var1 *= 0.0625f;
    float ln0 = dv0 * rsqrtf(var0 + 1e-5f) * gL[c] + btL[c];
    float ln1 = dv1 * rsqrtf(var1 + 1e-5f) * gL[16 + c] + btL[16 + c];
    float fac0 = fmaxf(ln0, 0.f) / (n0 + 1e-3f);
    float fac1 = fmaxf(ln1, 0.f) / (n1 + 1e-3f);
    float x0n = y0 * fac0;
    float x1n[3] = {y1v[0] * fac1, y1v[1] * fac1, y1v[2] * fac1};
    xs0[(size_t)n * 16 + c] = x0n;
    float* xo = xs1 + (size_t)n * 48 + c * 3;
    xo[0] = x1n[0]; xo[1] = x1n[1]; xo[2] = x1n[2];

    // ---- fused next-layer q ----
    if (wq_next) {
        __builtin_amdgcn_wave_barrier();
        in0[8 + c] = x0n;
        in1[24 + c * 3 + 0] = x1n[0];
        in1[24 + c * 3 + 1] = x1n[1];
        in1[24 + c * 3 + 2] = x1n[2];
        __builtin_amdgcn_wave_barrier();
        int compA = 2 * l16, compB = compA + 1;
#pragma unroll
        for (int cb = 0; cb < 2; ++cb) {
            int comp = cb ? compB : compA;
            float a = 0.f;
            if (comp < 8) {
#pragma unroll
                for (int cc = 0; cc < 16; ++cc)
                    a += in0[8 + cc] * wq_next[cc * 8 + comp];
                q0[(size_t)n * 8 + comp] = a;
            } else {
                int idx = comp - 8, dd = idx / 3, mm = idx % 3;
#pragma unroll
                for (int cc = 0; cc < 16; ++cc)
                    a += in1[24 + cc * 3 + mm] * wq_next[128 + cc * 8 + dd];
                q1[(size_t)n * 24 + idx] = a;
            }
        }
    }
}

// ---------------- final output: segment-sum(vrow) + x @ wself ----------------
__global__ __launch_bounds__(256) void k_out(
    int N,
    const int* __restrict__ rowptr, const float* __restrict__ vrow,
    const float* __restrict__ xs0, const float* __restrict__ xs1,
    const float* __restrict__ wself,  // (2,16,8)
    float* __restrict__ out) {
    int tid = threadIdx.x;
    int wave = tid >> 6, lane = tid & 63;
    int sub = lane >> 4, l16 = lane & 15;
    int n = blockIdx.x * 16 + wave * 4 + sub;
    if (n >= N) n = N - 1;
    int base = rowptr[n], deg = rowptr[n + 1] - base;

    int c0 = 2 * l16, c1 = c0 + 1;
    float accA = 0.f, accB = 0.f;
    const float* vbase = &vrow[(size_t)base * 32 + c0];
    int j = 0;
    for (; j + 3 < deg; j += 4) {
        float2 v0 = *(const float2*)(vbase + (size_t)j * 32);
        float2 v1 = *(const float2*)(vbase + (size_t)(j + 1) * 32);
        float2 v2 = *(const float2*)(vbase + (size_t)(j + 2) * 32);
        float2 v3 = *(const float2*)(vbase + (size_t)(j + 3) * 32);
        accA += v0.x + v1.x + v2.x + v3.x;
        accB += v0.y + v1.y + v2.y + v3.y;
    }
    for (; j < deg; ++j) {
        float2 v = *(const float2*)(vbase + (size_t)j * 32);
        accA += v.x;
        accB += v.y;
    }
    if (c0 < 8) {
#pragma unroll
        for (int c = 0; c < 16; ++c) {
            float xv = xs0[(size_t)n * 16 + c];
            accA += xv * wself[c * 8 + c0];
            accB += xv * wself[c * 8 + c1];
        }
    } else {
        int dA = (c0 - 8) / 3, mA = (c0 - 8) % 3;
        int dB = (c1 - 8) / 3, mB = (c1 - 8) % 3;
#pragma unroll
        for (int c = 0; c < 16; ++c) {
            accA += xs1[(size_t)n * 48 + c * 3 + mA] * wself[128 + c * 8 + dA];
            accB += xs1[(size_t)n * 48 + c * 3 + mB] * wself[128 + c * 8 + dB];
        }
    }
    *(float2*)&out[(size_t)n * 32 + c0] = make_float2(accA, accB);
}

// ---------------------------------------------------------------------------
extern "C" void kernel_launch(void* const* d_in, const int* in_sizes, int n_in,
                              void* d_out, int out_size, void* d_ws, size_t ws_size,
                              hipStream_t stream) {
    const float* x0 = (const float*)d_in[0];
    const float* x1 = (const float*)d_in[1];
    const float* ef = (const float*)d_in[2];
    const float* b00 = (const float*)d_in[3];
    const float* b01 = (const float*)d_in[4];
    const float* b10 = (const float*)d_in[5];
    const float* b11 = (const float*)d_in[6];
    const float* kvw1 = (const float*)d_in[7];    // (2,4,16,16)
    const float* kvw2n = (const float*)d_in[8];   // (2,3,16,16,16)
    const float* kvw211 = (const float*)d_in[9];  // (2,16,16,16,3)
    const float* wq = (const float*)d_in[10];     // (2,2,16,8)
    const float* wproj = (const float*)d_in[11];  // (2,2,24,16)
    const float* gam = (const float*)d_in[12];    // (2,2,16)
    const float* bet = (const float*)d_in[13];
    const float* fcw1 = (const float*)d_in[14];    // (4,16,16)
    const float* fcw2n = (const float*)d_in[15];   // (3,16,8,16)
    const float* fcw211 = (const float*)d_in[16];  // (16,8,16,3)
    const float* fcself = (const float*)d_in[17];  // (2,16,8)
    const int* esrc = (const int*)d_in[18];
    const int* edst = (const int*)d_in[19];
    int N = in_sizes[0] / 16;
    int E = in_sizes[18];
    float* out = (float*)d_out;

    float* ws = (float*)d_ws;
    size_t off = 0;
    float* xs0 = ws + off; off += (size_t)N * 16;
    float* xs1 = ws + off; off += (size_t)N * 48;
    float* q0b = ws + off; off += (size_t)N * 8;
    float* q1b = ws + off; off += (size_t)N * 24;
    float* vrow = ws + off; off += (size_t)E * 32;
    float* zb = ws + off; off += (size_t)E * 4;
    int* counts = (int*)(ws + off); off += N;
    int* rowptr = (int*)(ws + off); off += N + 1;
    int* cursor = (int*)(ws + off); off += N;
    int* pose = (int*)(ws + off); off += E;
    off = (off + 3) & ~(size_t)3;
    unsigned short* efh = (unsigned short*)(ws + off); off += (size_t)E * 16 / 2;
    unsigned short* Wfrag = (unsigned short*)(ws + off); off += (size_t)156 * 64 * 8 / 2;

    const int tpb = 256;
    int ebl = (E + 255) / 256;
    int cblk = (E / 16 + 3) / 4;
    int nbl16 = (N + 15) / 16;

    int itot = 156 * 512 + N * 16 + N * 48 + E * 16 + N * 32;
    k_init<<<(itot + 255) / 256, tpb, 0, stream>>>(x0, x1, ef, kvw1, fcw1, kvw2n, kvw211,
                                                   fcw2n, fcw211, wq, xs0, xs1, efh,
                                                   Wfrag, q0b, q1b, N, E);
    hipMemsetAsync(counts, 0, (size_t)N * 4, stream);
    k_hist<<<ebl, tpb, 0, stream>>>(edst, counts, E);
    int CH = (N + 1023) / 1024;
    k_scan<<<1, 1024, 0, stream>>>(counts, rowptr, cursor, N, CH);
    k_scatter<<<ebl, tpb, 0, stream>>>(edst, cursor, pose, E);

    // layer 0
    k_conv<16, true><<<cblk, tpb, 0, stream>>>(E, esrc, edst, pose, xs0, xs1,
                                               b00, b01, b10, b11, efh, Wfrag, 0,
                                               q0b, q1b, vrow, zb);
    k_attn<<<nbl16, tpb, 0, stream>>>(N, rowptr, zb, vrow, wproj,
                                      gam, bet, xs0, xs1, wq + 256, q0b, q1b);
    // layer 1
    k_conv<16, true><<<cblk, tpb, 0, stream>>>(E, esrc, edst, pose, xs0, xs1,
                                               b00, b01, b10, b11, efh, Wfrag, 52,
                                               q0b, q1b, vrow, zb);
    k_attn<<<nbl16, tpb, 0, stream>>>(N, rowptr, zb, vrow, wproj + 768,
                                      gam + 32, bet + 32, xs0, xs1, nullptr, q0b, q1b);
    // final conv + output
    k_conv<8, false><<<cblk, tpb, 0, stream>>>(E, esrc, edst, pose, xs0, xs1,
                                               b00, b01, b10, b11, efh, Wfrag, 104,
                                               q0b, q1b, vrow, zb);
    k_out<<<nbl16, tpb, 0, stream>>>(N, rowptr, vrow, xs0, xs1, fcself, out);
}

// Round 12
// 291.897 us; speedup vs baseline: 1.0277x; 1.0245x over previous
//
#include <hip/hip_runtime.h>
#include <hip/hip_fp16.h>
#include <math.h>

// ---------------------------------------------------------------------------
// EquivariantNet forward — round 12.
// Conv body = r7 exactly (best measured, 45.5 us) with ONE change: the 27
// per-lane fp32 b11 loads become 7 uint2 loads of f16-prepacked b11h (halves
// b11 bytes; epilogue b00/b01/b10 stay fp32 — the r8 failure was f16 epilogue
// multipliers, not the operand path). Plus: xs copies deleted (layer 0 reads
// x0/x1 inputs directly), r10 merged-softmax attn, r11 fused k_init.
// Shapes: N=8192, E=131072, C=16, mid=16, KV=16, ckv=8, Co=8, HEADS=4, L=2
// ---------------------------------------------------------------------------

typedef _Float16 half8 __attribute__((ext_vector_type(8)));
typedef float f32x4 __attribute__((ext_vector_type(4)));

union AF {
    half8 h8;
    __half2 h2[4];
};
union U32h2 {
    unsigned u;
    __half2 h;
};

static __device__ __forceinline__ float h2f_lo(unsigned u) {
    U32h2 w; w.u = u; return __low2float(w.h);
}
static __device__ __forceinline__ float h2f_hi(unsigned u) {
    U32h2 w; w.u = u; return __high2float(w.h);
}

// ---------------- CSR build over edge_dst ----------------
__global__ void k_hist(const int* __restrict__ dst, int* __restrict__ counts, int E) {
    int e = blockIdx.x * 256 + threadIdx.x;
    if (e < E) atomicAdd(&counts[dst[e]], 1);
}

__global__ __launch_bounds__(1024) void k_scan(const int* __restrict__ counts,
                                               int* __restrict__ rowptr,
                                               int* __restrict__ cursor,
                                               int N, int CH) {
    __shared__ int part[1024];
    int t = threadIdx.x;
    int s = 0;
    for (int i = 0; i < CH; ++i) {
        int idx = t * CH + i;
        if (idx < N) s += counts[idx];
    }
    part[t] = s;
    __syncthreads();
    for (int off = 1; off < 1024; off <<= 1) {
        int v = (t >= off) ? part[t - off] : 0;
        __syncthreads();
        part[t] += v;
        __syncthreads();
    }
    int run = (t == 0) ? 0 : part[t - 1];
    for (int i = 0; i < CH; ++i) {
        int idx = t * CH + i;
        if (idx < N) {
            rowptr[idx] = run;
            cursor[idx] = run;
            run += counts[idx];
        }
    }
    if (t == 0) rowptr[N] = part[1023];
}

__global__ void k_scatter(const int* __restrict__ dst, int* __restrict__ cursor,
                          int* __restrict__ pose, int E) {
    int e = blockIdx.x * 256 + threadIdx.x;
    if (e < E) {
        int pos = atomicAdd(&cursor[dst[e]], 1);
        pose[e] = pos;
    }
}

// ---------------- fused init: W-frag permute + ef->f16 + layer0 q + b11h ----
// ranges: [0,79872) prepw | efh E*16 | q N*32 | b11h E*27
__global__ void k_init(const float* __restrict__ x0, const float* __restrict__ x1,
                       const float* __restrict__ ef, const float* __restrict__ b11,
                       const float* __restrict__ kvw1, const float* __restrict__ fcw1,
                       const float* __restrict__ kvw2n, const float* __restrict__ kvw211,
                       const float* __restrict__ fcw2n, const float* __restrict__ fcw211,
                       const float* __restrict__ wq,
                       unsigned short* __restrict__ efh,
                       unsigned short* __restrict__ Wfrag,
                       float* __restrict__ q0, float* __restrict__ q1,
                       unsigned short* __restrict__ b11h,
                       int N, int E) {
    int i = blockIdx.x * 256 + threadIdx.x;
    if (i < 156 * 64 * 8) {
        int t = i;
        int j = t & 7;
        int lane = (t >> 3) & 63;
        int row = t >> 9;
        int quad = lane >> 4, m = lane & 15;
        int c = row / 52, r = row % 52;
        int KVO = (c < 2) ? 16 : 8;
        const float* w1src = (c < 2) ? (kvw1 + c * 1024) : fcw1;
        const float* w2n = (c < 2) ? (kvw2n + c * 12288) : fcw2n;
        const float* w211 = (c < 2) ? (kvw211 + c * 12288) : fcw211;
        float v = 0.f;
        if (r < 4) {
            if (quad < 2) v = w1src[r * 256 + (quad * 8 + j) * 16 + m];
        } else if (r < 28) {
            int fam = (r - 4) >> 3, kk = (r - 4) & 7;
            int h = quad * 4 + ((j >> 1) & 3), ii = 2 * kk + (j & 1);
            if (m < KVO) v = w2n[((fam * 16 + h) * KVO + m) * 16 + ii];
        } else {
            int kk2 = r - 28;
            int h = quad * 4 + ((j >> 1) & 3);
            int ifx = 2 * kk2 + (j & 1);
            int ii = ifx / 3, f = ifx % 3;
            if (m < KVO) v = w211[((h * KVO + m) * 16 + ii) * 3 + f];
        }
        Wfrag[t] = __half_as_ushort(__float2half(v));
        return;
    }
    i -= 156 * 64 * 8;
    if (i < E * 16) { efh[i] = __half_as_ushort(__float2half(ef[i])); return; }
    i -= E * 16;
    if (i < N * 32) {
        int n = i >> 5, comp = i & 31;
        if (comp < 8) {
            float a = 0.f;
#pragma unroll
            for (int c = 0; c < 16; ++c) a += x0[n * 16 + c] * wq[c * 8 + comp];
            q0[n * 8 + comp] = a;
        } else {
            int idx = comp - 8, dd = idx / 3, mm = idx % 3;
            float a = 0.f;
#pragma unroll
            for (int c = 0; c < 16; ++c) a += x1[n * 48 + c * 3 + mm] * wq[128 + c * 8 + dd];
            q1[n * 24 + dd * 3 + mm] = a;
        }
        return;
    }
    i -= N * 32;
    if (i < E * 27) {
        int e = i / 27, k = i - e * 27;
        b11h[(size_t)e * 28 + k] = __half_as_ushort(__float2half(b11[i]));
    }
}

// ---------------- fused MFMA conv (+H, +z), f16, pair-shared-H builds --------
// vrow[pos][32]: [0..8) scalar d | [8..32) 8+d*3+m.  zb[pos][4]: per-head z.
// Body identical to r7 except b11 read: 7 uint2 f16 loads (b11h) vs 27 dwords.
template <int KVO, bool DO_Z>
__global__ __launch_bounds__(256) void k_conv(
    int E,
    const int* __restrict__ src, const int* __restrict__ dst,
    const int* __restrict__ pose,
    const float* __restrict__ xs0, const float* __restrict__ xs1,
    const float* __restrict__ b00, const float* __restrict__ b01,
    const float* __restrict__ b10,
    const unsigned short* __restrict__ b11h,   // (E,28) f16
    const unsigned short* __restrict__ efh,    // (E,16) f16
    const unsigned short* __restrict__ Wfrag,  // frag-ordered weights (f16)
    int wbase,
    const float* __restrict__ q0, const float* __restrict__ q1,
    float* __restrict__ vrow, float* __restrict__ zb)
{
    // xB pairs: [wave][m][p*24 + u], u = if/2 (0..23), each uint = half2 pair
    __shared__ __align__(16) unsigned xBL[4][16 * 74];
    int tid = threadIdx.x;
    int wave = tid >> 6, lane = tid & 63;
    int tile = blockIdx.x * 4 + wave;
    if (tile * 16 >= E) return;
    int m = lane & 15, quad = lane >> 4;
    int e0 = tile * 16;
    int me = e0 + m;
    int s = src[me];
    unsigned* xw = xBL[wave];
    const half8* W8 = (const half8*)Wfrag;

    // ---- xB[p][if] = sum_q x1[i][q]*b11[p][q][f]; quad covers if [quad*12,+12) ----
    {
        float x1c[12];
        const float4* xp = (const float4*)(xs1 + (size_t)s * 48 + quad * 12);
#pragma unroll
        for (int cc = 0; cc < 3; ++cc) {
            float4 v = xp[cc];
            x1c[cc * 4 + 0] = v.x; x1c[cc * 4 + 1] = v.y;
            x1c[cc * 4 + 2] = v.z; x1c[cc * 4 + 3] = v.w;
        }
        float b11r[27];
        {
            const uint2* bp = (const uint2*)(b11h + (size_t)me * 28);
#pragma unroll
            for (int t = 0; t < 6; ++t) {
                uint2 uu = bp[t];
                b11r[4 * t + 0] = h2f_lo(uu.x);
                b11r[4 * t + 1] = h2f_hi(uu.x);
                b11r[4 * t + 2] = h2f_lo(uu.y);
                b11r[4 * t + 3] = h2f_hi(uu.y);
            }
            uint2 uu = bp[6];
            b11r[24] = h2f_lo(uu.x);
            b11r[25] = h2f_hi(uu.x);
            b11r[26] = h2f_lo(uu.y);
        }
#pragma unroll
        for (int p = 0; p < 3; ++p) {
            float vals[12];
#pragma unroll
            for (int i2 = 0; i2 < 4; ++i2) {
#pragma unroll
                for (int f = 0; f < 3; ++f) {
                    float a = 0.f;
#pragma unroll
                    for (int q = 0; q < 3; ++q) a += x1c[i2 * 3 + q] * b11r[p * 9 + q * 3 + f];
                    vals[i2 * 3 + f] = a;
                }
            }
            unsigned uu[6];
#pragma unroll
            for (int u = 0; u < 6; ++u) {
                U32h2 w;
                w.h = __float22half2_rn(make_float2(vals[2 * u], vals[2 * u + 1]));
                uu[u] = w.u;
            }
            int boff = m * 74 + p * 24 + quad * 6;
            *(uint2*)&xw[boff + 0] = make_uint2(uu[0], uu[1]);
            *(uint2*)&xw[boff + 2] = make_uint2(uu[2], uu[3]);
            *(uint2*)&xw[boff + 4] = make_uint2(uu[4], uu[5]);
        }
    }
    __syncthreads();

    // ---- x0 / t10 rows as natural half2 pairs (8 regs each) ----
    __half2 x0p[8], t10p[8];
    {
        const float4* p = (const float4*)(xs0 + (size_t)s * 16);
#pragma unroll
        for (int k = 0; k < 4; ++k) {
            float4 v = p[k];
            x0p[2 * k + 0] = __float22half2_rn(make_float2(v.x, v.y));
            x0p[2 * k + 1] = __float22half2_rn(make_float2(v.z, v.w));
        }
        float bq0 = b10[(size_t)me * 3 + 0], bq1 = b10[(size_t)me * 3 + 1],
              bq2 = b10[(size_t)me * 3 + 2];
        const float4* xp = (const float4*)(xs1 + (size_t)s * 48);
        float tf[16];
#pragma unroll
        for (int g = 0; g < 4; ++g) {
            float4 a = xp[g * 3 + 0], b = xp[g * 3 + 1], cc = xp[g * 3 + 2];
            float xf[12] = {a.x, a.y, a.z, a.w, b.x, b.y, b.z, b.w, cc.x, cc.y, cc.z, cc.w};
#pragma unroll
            for (int i2 = 0; i2 < 4; ++i2)
                tf[g * 4 + i2] = bq0 * xf[i2 * 3] + bq1 * xf[i2 * 3 + 1] + bq2 * xf[i2 * 3 + 2];
        }
#pragma unroll
        for (int k = 0; k < 8; ++k)
            t10p[k] = __float22half2_rn(make_float2(tf[2 * k], tf[2 * k + 1]));
    }

    // ---- H via 4 f16 MFMAs -> dup-half2 per (pp, t): H[pp][h=quad*4+t] ----
    __half2 Hd[4][4];
    {
        half8 efr = {0, 0, 0, 0, 0, 0, 0, 0};
        if (quad < 2) efr = *(const half8*)(efh + (size_t)me * 16 + quad * 8);
        f32x4 z4 = {0.f, 0.f, 0.f, 0.f};
#pragma unroll
        for (int pp = 0; pp < 4; ++pp) {
            half8 w1f = W8[(size_t)(wbase + pp) * 64 + lane];
            f32x4 hacc = __builtin_amdgcn_mfma_f32_16x16x32_f16(w1f, efr, z4, 0, 0, 0);
#pragma unroll
            for (int r = 0; r < 4; ++r)
                Hd[pp][r] = __float2half2_rn(__float2half(fmaxf(hacc[r], 0.f)));
        }
    }

    f32x4 acc0 = {0.f, 0.f, 0.f, 0.f}, acc1 = acc0, acc2 = acc0;
    f32x4 accP0 = acc0, accP1 = acc0, accP2 = acc0;

    // ---- loop1: fams 0,1,2 (K=256): A.h2[t] = Hd[pp][t] * (x[2kk],x[2kk+1]) ----
#pragma unroll
    for (int kk = 0; kk < 8; ++kk) {
        __half2 xp_ = x0p[kk], tp_ = t10p[kk];
        AF a0, a1, a2;
#pragma unroll
        for (int t = 0; t < 4; ++t) {
            a0.h2[t] = __hmul2(Hd[0][t], xp_);
            a1.h2[t] = __hmul2(Hd[1][t], xp_);
            a2.h2[t] = __hmul2(Hd[2][t], tp_);
        }
        half8 w0 = W8[(size_t)(wbase + 4 + kk) * 64 + lane];
        half8 w1f = W8[(size_t)(wbase + 12 + kk) * 64 + lane];
        half8 w2f = W8[(size_t)(wbase + 20 + kk) * 64 + lane];
        acc0 = __builtin_amdgcn_mfma_f32_16x16x32_f16(w0, a0.h8, acc0, 0, 0, 0);
        acc1 = __builtin_amdgcn_mfma_f32_16x16x32_f16(w1f, a1.h8, acc1, 0, 0, 0);
        acc2 = __builtin_amdgcn_mfma_f32_16x16x32_f16(w2f, a2.h8, acc2, 0, 0, 0);
    }

    // ---- loop2: fam3 (K=768), MFMA kk2=2kko+t covers if-pair u=kk2 ----
#pragma unroll
    for (int kko = 0; kko < 12; ++kko) {
        uint2 xu0 = *(const uint2*)&xw[m * 74 + 0 * 24 + 2 * kko];
        uint2 xu1 = *(const uint2*)&xw[m * 74 + 1 * 24 + 2 * kko];
        uint2 xu2 = *(const uint2*)&xw[m * 74 + 2 * 24 + 2 * kko];
        unsigned pv0[2] = {xu0.x, xu0.y};
        unsigned pv1[2] = {xu1.x, xu1.y};
        unsigned pv2[2] = {xu2.x, xu2.y};
#pragma unroll
        for (int t = 0; t < 2; ++t) {
            U32h2 u0, u1, u2;
            u0.u = pv0[t]; u1.u = pv1[t]; u2.u = pv2[t];
            AF a0, a1, a2;
#pragma unroll
            for (int r = 0; r < 4; ++r) {
                a0.h2[r] = __hmul2(Hd[3][r], u0.h);
                a1.h2[r] = __hmul2(Hd[3][r], u1.h);
                a2.h2[r] = __hmul2(Hd[3][r], u2.h);
            }
            half8 wf = W8[(size_t)(wbase + 28 + 2 * kko + t) * 64 + lane];
            accP0 = __builtin_amdgcn_mfma_f32_16x16x32_f16(wf, a0.h8, accP0, 0, 0, 0);
            accP1 = __builtin_amdgcn_mfma_f32_16x16x32_f16(wf, a1.h8, accP1, 0, 0, 0);
            accP2 = __builtin_amdgcn_mfma_f32_16x16x32_f16(wf, a2.h8, accP2, 0, 0, 0);
        }
    }

    // ---- epilogue: lane holds oo = quad*4+r for edge me (b's fp32!) ----
    float b00r = b00[me];
    float b01r0 = b01[(size_t)me * 3 + 0], b01r1 = b01[(size_t)me * 3 + 1],
          b01r2 = b01[(size_t)me * 3 + 2];
    float o0v[4], o1v[4][3];
#pragma unroll
    for (int r = 0; r < 4; ++r) {
        o0v[r] = b00r * acc0[r] + acc2[r];
        o1v[r][0] = b01r0 * acc1[r] + accP0[r];
        o1v[r][1] = b01r1 * acc1[r] + accP1[r];
        o1v[r][2] = b01r2 * acc1[r] + accP2[r];
    }
    int pos = pose[me];
    bool doStore = DO_Z ? (quad >= 2) : (quad < 2);
    if (doStore) {
        int qa = DO_Z ? (quad - 2) : quad;
        float* vp = vrow + (size_t)pos * 32;
        *(float4*)&vp[qa * 4] = make_float4(o0v[0], o0v[1], o0v[2], o0v[3]);
        float* p1 = vp + 8 + qa * 12;
        *(float4*)&p1[0] = make_float4(o1v[0][0], o1v[0][1], o1v[0][2], o1v[1][0]);
        *(float4*)&p1[4] = make_float4(o1v[1][1], o1v[1][2], o1v[2][0], o1v[2][1]);
        *(float4*)&p1[8] = make_float4(o1v[2][2], o1v[3][0], o1v[3][1], o1v[3][2]);
    }
    if (DO_Z && quad < 2) {
        int n = dst[me];
        float4 q0v = *(const float4*)&q0[(size_t)n * 8 + quad * 4];
        const float4* q1p = (const float4*)&q1[(size_t)n * 24 + quad * 12];
        float4 qa4 = q1p[0], qb4 = q1p[1], qc4 = q1p[2];
        float q1f[12] = {qa4.x, qa4.y, qa4.z, qa4.w, qb4.x, qb4.y, qb4.z, qb4.w,
                         qc4.x, qc4.y, qc4.z, qc4.w};
        float q0f[4] = {q0v.x, q0v.y, q0v.z, q0v.w};
        float zh0 = 0.f, zh1 = 0.f;
#pragma unroll
        for (int r = 0; r < 4; ++r) {
            float tt = q0f[r] * o0v[r] + q1f[r * 3 + 0] * o1v[r][0] +
                       q1f[r * 3 + 1] * o1v[r][1] + q1f[r * 3 + 2] * o1v[r][2];
            if (r < 2) zh0 += tt;
            else zh1 += tt;
        }
        const float scale = 0.35355339059327373f;  // 1/sqrt(8)
        *(float2*)&zb[(size_t)pos * 4 + quad * 2] = make_float2(zh0 * scale, zh1 * scale);
    }
}

// ---------------- per-node: softmax + aggregate + proj + SE3-norm (+next q) --
// 4 nodes per wave, 16 lanes per node; 16 nodes per block. CSR-ordered reads.
// xr0/xr1 = residual-read source (x inputs for layer 0, xs for layer 1);
// xs0/xs1 = write destination.
__global__ __launch_bounds__(256) void k_attn(
    int N,
    const int* __restrict__ rowptr,
    const float* __restrict__ zb, const float* __restrict__ vrow,
    const float* __restrict__ wproj,  // (2,24,16)
    const float* __restrict__ gamma, const float* __restrict__ beta,  // (2,16)
    const float* __restrict__ xr0, const float* __restrict__ xr1,
    float* __restrict__ xs0, float* __restrict__ xs1,
    const float* __restrict__ wq_next,  // next layer wq (2,16,8) or nullptr
    float* __restrict__ q0, float* __restrict__ q1) {
    __shared__ float wpL[768];
    __shared__ float gL[32], btL[32];
    __shared__ float inb[16][100];   // per node: in0[24] + in1[72]
    __shared__ float aw[16][16][4];  // per node: alpha chunk (unnormalized)
    int tid = threadIdx.x;
    for (int i = tid; i < 768; i += 256) wpL[i] = wproj[i];
    if (tid < 32) { gL[tid] = gamma[tid]; btL[tid] = beta[tid]; }
    int wave = tid >> 6, lane = tid & 63;
    int sub = lane >> 4, l16 = lane & 15;
    int nodeIdx = wave * 4 + sub;
    int n = blockIdx.x * 16 + nodeIdx;
    if (n >= N) n = N - 1;
    int base = rowptr[n], deg = rowptr[n + 1] - base;
    const float4* zb4 = (const float4*)zb;

    // pass 1: per-head max (coalesced)
    float mx0 = -INFINITY, mx1 = -INFINITY, mx2 = -INFINITY, mx3 = -INFINITY;
    for (int j = l16; j < deg; j += 16) {
        float4 zv = zb4[base + j];
        mx0 = fmaxf(mx0, zv.x); mx1 = fmaxf(mx1, zv.y);
        mx2 = fmaxf(mx2, zv.z); mx3 = fmaxf(mx3, zv.w);
    }
#pragma unroll
    for (int off = 1; off < 16; off <<= 1) {
        mx0 = fmaxf(mx0, __shfl_xor(mx0, off));
        mx1 = fmaxf(mx1, __shfl_xor(mx1, off));
        mx2 = fmaxf(mx2, __shfl_xor(mx2, off));
        mx3 = fmaxf(mx3, __shfl_xor(mx3, off));
    }
    if (!isfinite(mx0)) mx0 = 0.f;
    if (!isfinite(mx1)) mx1 = 0.f;
    if (!isfinite(mx2)) mx2 = 0.f;
    if (!isfinite(mx3)) mx3 = 0.f;

    // pass 2 (merged): unnormalized alpha chunks -> LDS, accumulate + per-lane sums
    int c0 = 2 * l16, c1 = c0 + 1;
    int hA = ((c0 < 8) ? c0 : (c0 - 8) / 3) >> 1;
    int hB = ((c1 < 8) ? c1 : (c1 - 8) / 3) >> 1;
    float s0 = 0.f, s1 = 0.f, s2 = 0.f, s3 = 0.f;
    float accA = 0.f, accB = 0.f;
    for (int j0 = 0; j0 < deg; j0 += 16) {
        int j = j0 + l16;
        float4 a4 = make_float4(0.f, 0.f, 0.f, 0.f);
        if (j < deg) {
            float4 zv = zb4[base + j];
            a4.x = __expf(zv.x - mx0);
            a4.y = __expf(zv.y - mx1);
            a4.z = __expf(zv.z - mx2);
            a4.w = __expf(zv.w - mx3);
            s0 += a4.x; s1 += a4.y; s2 += a4.z; s3 += a4.w;
        }
        *(float4*)&aw[nodeIdx][l16][0] = a4;
        __builtin_amdgcn_wave_barrier();
        int cnt = min(16, deg - j0);
        const float* vbase = &vrow[(size_t)(base + j0) * 32 + c0];
        int jj = 0;
        for (; jj + 3 < cnt; jj += 4) {
            float2 v0 = *(const float2*)(vbase + (size_t)jj * 32);
            float2 v1 = *(const float2*)(vbase + (size_t)(jj + 1) * 32);
            float2 v2 = *(const float2*)(vbase + (size_t)(jj + 2) * 32);
            float2 v3 = *(const float2*)(vbase + (size_t)(jj + 3) * 32);
            accA += aw[nodeIdx][jj][hA] * v0.x + aw[nodeIdx][jj + 1][hA] * v1.x +
                    aw[nodeIdx][jj + 2][hA] * v2.x + aw[nodeIdx][jj + 3][hA] * v3.x;
            accB += aw[nodeIdx][jj][hB] * v0.y + aw[nodeIdx][jj + 1][hB] * v1.y +
                    aw[nodeIdx][jj + 2][hB] * v2.y + aw[nodeIdx][jj + 3][hB] * v3.y;
        }
        for (; jj < cnt; ++jj) {
            float2 v = *(const float2*)(vbase + (size_t)jj * 32);
            accA += aw[nodeIdx][jj][hA] * v.x;
            accB += aw[nodeIdx][jj][hB] * v.y;
        }
        __builtin_amdgcn_wave_barrier();
    }
#pragma unroll
    for (int off = 1; off < 16; off <<= 1) {
        s0 += __shfl_xor(s0, off); s1 += __shfl_xor(s1, off);
        s2 += __shfl_xor(s2, off); s3 += __shfl_xor(s3, off);
    }
    float inva[4] = {1.f / (s0 + 1e-9f), 1.f / (s1 + 1e-9f),
                     1.f / (s2 + 1e-9f), 1.f / (s3 + 1e-9f)};
    accA *= inva[hA];
    accB *= inva[hB];

    // stage concat([o, x]) into LDS
    float* in0 = inb[nodeIdx];
    float* in1 = in0 + 24;
    if (c0 < 8) { in0[c0] = accA; in0[c1] = accB; }
    else        { in1[c0 - 8] = accA; in1[c1 - 8] = accB; }
    in0[8 + l16] = xr0[(size_t)n * 16 + l16];
    {
        const float* xp = xr1 + (size_t)n * 48 + l16 * 3;
        in1[24 + l16 * 3 + 0] = xp[0];
        in1[24 + l16 * 3 + 1] = xp[1];
        in1[24 + l16 * 3 + 2] = xp[2];
    }
    __syncthreads();

    // projection: each lane -> 4 outputs of its node
    int c = l16;
    float y0 = 0.f;
#pragma unroll
    for (int j = 0; j < 24; ++j) y0 += in0[j] * wpL[j * 16 + c];
    float y1v[3];
#pragma unroll
    for (int mm = 0; mm < 3; ++mm) {
        float y = 0.f;
#pragma unroll
        for (int j = 0; j < 24; ++j) y += in1[j * 3 + mm] * wpL[384 + j * 16 + c];
        y1v[mm] = y;
    }
    float n0 = sqrtf(y0 * y0 + 1e-12f);
    float n1 = sqrtf(y1v[0] * y1v[0] + y1v[1] * y1v[1] + y1v[2] * y1v[2] + 1e-12f);
    float mu0 = n0, mu1 = n1;
#pragma unroll
    for (int off = 1; off < 16; off <<= 1) {
        mu0 += __shfl_xor(mu0, off);
        mu1 += __shfl_xor(mu1, off);
    }
    mu0 *= 0.0625f; mu1 *= 0.0625f;
    float dv0 = n0 - mu0, dv1 = n1 - mu1;
    float var0 = dv0 * dv0, var1 = dv1 * dv1;
#pragma unroll
    for (int off = 1; off < 16; off <<= 1) {
        var0 += __shfl_xor(var0, off);
        var1 += __shfl_xor(var1, off);
    }
    var0 *= 0.0625f; var1 *= 0.0625f;
    float ln0 = dv0 * rsqrtf(var0 + 1e-5f) * gL[c] + btL[c];
    float ln1 = dv1 * rsqrtf(var1 + 1e-5f) * gL[16 + c] + btL[16 + c];
    float fac0 = fmaxf(ln0, 0.f) / (n0 + 1e-3f);
    float fac1 = fmaxf(ln1, 0.f) / (n1 + 1e-3f);
    float x0n = y0 * fac0;
    float x1n[3] = {y1v[0] * fac1, y1v[1] * fac1, y1v[2] * fac1};
    xs0[(size_t)n * 16 + c] = x0n;
    float* xo = xs1 + (size_t)n * 48 + c * 3;
    xo[0] = x1n[0]; xo[1] = x1n[1]; xo[2] = x1n[2];

    // ---- fused next-layer q ----
    if (wq_next) {
        __builtin_amdgcn_wave_barrier();
        in0[8 + c] = x0n;
        in1[24 + c * 3 + 0] = x1n[0];
        in1[24 + c * 3 + 1] = x1n[1];
        in1[24 + c * 3 + 2] = x1n[2];
        __builtin_amdgcn_wave_barrier();
        int compA = 2 * l16, compB = compA + 1;
#pragma unroll
        for (int cb = 0; cb < 2; ++cb) {
            int comp = cb ? compB : compA;
            float a = 0.f;
            if (comp < 8) {
#pragma unroll
                for (int cc = 0; cc < 16; ++cc)
                    a += in0[8 + cc] * wq_next[cc * 8 + comp];
                q0[(size_t)n * 8 + comp] = a;
            } else {
                int idx = comp - 8, dd = idx / 3, mm = idx % 3;
#pragma unroll
                for (int cc = 0; cc < 16; ++cc)
                    a += in1[24 + cc * 3 + mm] * wq_next[128 + cc * 8 + dd];
                q1[(size_t)n * 24 + idx] = a;
            }
        }
    }
}

// ---------------- final output: segment-sum(vrow) + x @ wself ----------------
__global__ __launch_bounds__(256) void k_out(
    int N,
    const int* __restrict__ rowptr, const float* __restrict__ vrow,
    const float* __restrict__ xs0, const float* __restrict__ xs1,
    const float* __restrict__ wself,  // (2,16,8)
    float* __restrict__ out) {
    int tid = threadIdx.x;
    int wave = tid >> 6, lane = tid & 63;
    int sub = lane >> 4, l16 = lane & 15;
    int n = blockIdx.x * 16 + wave * 4 + sub;
    if (n >= N) n = N - 1;
    int base = rowptr[n], deg = rowptr[n + 1] - base;

    int c0 = 2 * l16, c1 = c0 + 1;
    float accA = 0.f, accB = 0.f;
    const float* vbase = &vrow[(size_t)base * 32 + c0];
    int j = 0;
    for (; j + 3 < deg; j += 4) {
        float2 v0 = *(const float2*)(vbase + (size_t)j * 32);
        float2 v1 = *(const float2*)(vbase + (size_t)(j + 1) * 32);
        float2 v2 = *(const float2*)(vbase + (size_t)(j + 2) * 32);
        float2 v3 = *(const float2*)(vbase + (size_t)(j + 3) * 32);
        accA += v0.x + v1.x + v2.x + v3.x;
        accB += v0.y + v1.y + v2.y + v3.y;
    }
    for (; j < deg; ++j) {
        float2 v = *(const float2*)(vbase + (size_t)j * 32);
        accA += v.x;
        accB += v.y;
    }
    if (c0 < 8) {
#pragma unroll
        for (int c = 0; c < 16; ++c) {
            float xv = xs0[(size_t)n * 16 + c];
            accA += xv * wself[c * 8 + c0];
            accB += xv * wself[c * 8 + c1];
        }
    } else {
        int dA = (c0 - 8) / 3, mA = (c0 - 8) % 3;
        int dB = (c1 - 8) / 3, mB = (c1 - 8) % 3;
#pragma unroll
        for (int c = 0; c < 16; ++c) {
            accA += xs1[(size_t)n * 48 + c * 3 + mA] * wself[128 + c * 8 + dA];
            accB += xs1[(size_t)n * 48 + c * 3 + mB] * wself[128 + c * 8 + dB];
        }
    }
    *(float2*)&out[(size_t)n * 32 + c0] = make_float2(accA, accB);
}

// ---------------------------------------------------------------------------
extern "C" void kernel_launch(void* const* d_in, const int* in_sizes, int n_in,
                              void* d_out, int out_size, void* d_ws, size_t ws_size,
                              hipStream_t stream) {
    const float* x0 = (const float*)d_in[0];
    const float* x1 = (const float*)d_in[1];
    const float* ef = (const float*)d_in[2];
    const float* b00 = (const float*)d_in[3];
    const float* b01 = (const float*)d_in[4];
    const float* b10 = (const float*)d_in[5];
    const float* b11 = (const float*)d_in[6];
    const float* kvw1 = (const float*)d_in[7];    // (2,4,16,16)
    const float* kvw2n = (const float*)d_in[8];   // (2,3,16,16,16)
    const float* kvw211 = (const float*)d_in[9];  // (2,16,16,16,3)
    const float* wq = (const float*)d_in[10];     // (2,2,16,8)
    const float* wproj = (const float*)d_in[11];  // (2,2,24,16)
    const float* gam = (const float*)d_in[12];    // (2,2,16)
    const float* bet = (const float*)d_in[13];
    const float* fcw1 = (const float*)d_in[14];    // (4,16,16)
    const float* fcw2n = (const float*)d_in[15];   // (3,16,8,16)
    const float* fcw211 = (const float*)d_in[16];  // (16,8,16,3)
    const float* fcself = (const float*)d_in[17];  // (2,16,8)
    const int* esrc = (const int*)d_in[18];
    const int* edst = (const int*)d_in[19];
    int N = in_sizes[0] / 16;
    int E = in_sizes[18];
    float* out = (float*)d_out;

    float* ws = (float*)d_ws;
    size_t off = 0;
    float* xs0 = ws + off; off += (size_t)N * 16;
    float* xs1 = ws + off; off += (size_t)N * 48;
    float* q0b = ws + off; off += (size_t)N * 8;
    float* q1b = ws + off; off += (size_t)N * 24;
    float* vrow = ws + off; off += (size_t)E * 32;
    float* zb = ws + off; off += (size_t)E * 4;
    int* counts = (int*)(ws + off); off += N;
    int* rowptr = (int*)(ws + off); off += N + 1;
    int* cursor = (int*)(ws + off); off += N;
    int* pose = (int*)(ws + off); off += E;
    off = (off + 3) & ~(size_t)3;
    unsigned short* efh = (unsigned short*)(ws + off); off += (size_t)E * 16 / 2;
    unsigned short* b11h = (unsigned short*)(ws + off); off += (size_t)E * 28 / 2;
    unsigned short* Wfrag = (unsigned short*)(ws + off); off += (size_t)156 * 64 * 8 / 2;

    const int tpb = 256;
    int ebl = (E + 255) / 256;
    int cblk = (E / 16 + 3) / 4;
    int nbl16 = (N + 15) / 16;

    int itot = 156 * 512 + E * 16 + N * 32 + E * 27;
    k_init<<<(itot + 255) / 256, tpb, 0, stream>>>(x0, x1, ef, b11, kvw1, fcw1, kvw2n,
                                                   kvw211, fcw2n, fcw211, wq, efh,
                                                   Wfrag, q0b, q1b, b11h, N, E);
    hipMemsetAsync(counts, 0, (size_t)N * 4, stream);
    k_hist<<<ebl, tpb, 0, stream>>>(edst, counts, E);
    int CH = (N + 1023) / 1024;
    k_scan<<<1, 1024, 0, stream>>>(counts, rowptr, cursor, N, CH);
    k_scatter<<<ebl, tpb, 0, stream>>>(edst, cursor, pose, E);

    // layer 0 (reads x inputs directly; attn writes xs)
    k_conv<16, true><<<cblk, tpb, 0, stream>>>(E, esrc, edst, pose, x0, x1,
                                               b00, b01, b10, b11h, efh, Wfrag, 0,
                                               q0b, q1b, vrow, zb);
    k_attn<<<nbl16, tpb, 0, stream>>>(N, rowptr, zb, vrow, wproj, gam, bet,
                                      x0, x1, xs0, xs1, wq + 256, q0b, q1b);
    // layer 1
    k_conv<16, true><<<cblk, tpb, 0, stream>>>(E, esrc, edst, pose, xs0, xs1,
                                               b00, b01, b10, b11h, efh, Wfrag, 52,
                                               q0b, q1b, vrow, zb);
    k_attn<<<nbl16, tpb, 0, stream>>>(N, rowptr, zb, vrow, wproj + 768, gam + 32,
                                      bet + 32, xs0, xs1, xs0, xs1, nullptr, q0b, q1b);
    // final conv + output
    k_conv<8, false><<<cblk, tpb, 0, stream>>>(E, esrc, edst, pose, xs0, xs1,
                                               b00, b01, b10, b11h, efh, Wfrag, 104,
                                               q0b, q1b, vrow, zb);
    k_out<<<nbl16, tpb, 0, stream>>>(N, rowptr, vrow, xs0, xs1, fcself, out);
}